// Round 1
// baseline (341.347 us; speedup 1.0000x reference)
//
#include <hip/hip_runtime.h>

// Problem constants (fixed by reference)
#define BB 8
#define NN 1024
#define HH 768
#define NHEAD 12
#define HD 64
#define NSEG 8192            // B*N
#define QKVN 2304            // 3*H
#define NSCAN 1024           // scan block threads

typedef unsigned short u16;
typedef __attribute__((ext_vector_type(8))) short bf16x8;
typedef __attribute__((ext_vector_type(4))) float f32x4;

__device__ __forceinline__ float bf2f(u16 v) {
  return __uint_as_float(((unsigned)v) << 16);
}
__device__ __forceinline__ u16 f2bf(float f) {
  unsigned u = __float_as_uint(f);
  u += 0x7FFFu + ((u >> 16) & 1u);
  return (u16)(u >> 16);
}

// ---------------- prep: cast node_states fp32 -> bf16 ----------------
__global__ void cast_x_kernel(const float* __restrict__ X, u16* __restrict__ Xb) {
  int i = blockIdx.x * blockDim.x + threadIdx.x;   // one float4 per thread
  float4 f = ((const float4*)X)[i];
  ushort4 o;
  o.x = f2bf(f.x); o.y = f2bf(f.y); o.z = f2bf(f.z); o.w = f2bf(f.w);
  ((ushort4*)Xb)[i] = o;
}

// ------------- prep: build Wt[n][k] = Wsel[k][n] in bf16 -------------
// Wt is (2304 x 768): rows 0..767 = Wq^T, 768..1535 = Wk^T, 1536.. = Wv^T
__global__ void transpose_w_kernel(const float* __restrict__ Wq,
                                   const float* __restrict__ Wk,
                                   const float* __restrict__ Wv,
                                   u16* __restrict__ Wt) {
  __shared__ float tile[32][33];
  int n0 = blockIdx.x * 32;   // 0..2303 (output row / source col)
  int k0 = blockIdx.y * 32;   // 0..767
  const float* W = (n0 < HH) ? Wq : (n0 < 2 * HH ? Wk : Wv);
  int nb = n0 & (HH - 1);     // H=768 not pow2! use modulo-ish: n0 % 768
  nb = n0 - (n0 < HH ? 0 : (n0 < 2 * HH ? HH : 2 * HH));
  int tx = threadIdx.x, ty = threadIdx.y;   // block (32, 8)
#pragma unroll
  for (int r = 0; r < 4; ++r)
    tile[ty + 8 * r][tx] = W[(k0 + ty + 8 * r) * HH + nb + tx];
  __syncthreads();
#pragma unroll
  for (int r = 0; r < 4; ++r)
    Wt[(n0 + ty + 8 * r) * HH + k0 + tx] = f2bf(tile[tx][ty + 8 * r]);
}

// ---------------- CSR build ----------------
__global__ void count_kernel(const int* __restrict__ EI, int* __restrict__ counts, int E) {
  int e = blockIdx.x * blockDim.x + threadIdx.x;
  if (e >= E) return;
  int seg = EI[e] * NN + EI[E + e];   // eb*N + ei
  atomicAdd(&counts[seg], 1);
}

__global__ void scan_kernel(const int* __restrict__ counts, int* __restrict__ offsets) {
  __shared__ int sdata[NSCAN];
  int t = threadIdx.x;
  int base = t * 8;
  int loc[8];
  int run = 0;
#pragma unroll
  for (int r = 0; r < 8; ++r) { loc[r] = run; run += counts[base + r]; }
  sdata[t] = run;
  __syncthreads();
  for (int off = 1; off < NSCAN; off <<= 1) {
    int v = (t >= off) ? sdata[t - off] : 0;
    __syncthreads();
    sdata[t] += v;
    __syncthreads();
  }
  int excl = sdata[t] - run;
#pragma unroll
  for (int r = 0; r < 8; ++r) offsets[base + r] = excl + loc[r];
}

__global__ void scatter_kernel(const int* __restrict__ EI,
                               const int* __restrict__ offsets,
                               int* __restrict__ cursor,
                               int* __restrict__ tailrow, int E) {
  int e = blockIdx.x * blockDim.x + threadIdx.x;
  if (e >= E) return;
  int b = EI[e];
  int seg = b * NN + EI[E + e];
  int j = EI[2 * E + e];
  int pos = atomicAdd(&cursor[seg], 1);
  tailrow[offsets[seg] + pos] = b * NN + j;
}

// ---------------- fused QKV GEMM: (8192x768) @ (768x2304), bf16 MFMA ----------------
// m97-style: 128x128 block tile, 4 waves (2x2), each wave 4x4 16x16x32 MFMAs,
// global_load_lds width-16 staging (LDS dst = wave-uniform base + lane*16).
#define BM 128
#define BN 128
#define BK 32

__global__ __launch_bounds__(256) void gemm_kernel(const u16* __restrict__ Xb,
                                                   const u16* __restrict__ Wt,
                                                   u16* __restrict__ QKV) {
  __shared__ u16 As[BM * BK];   // 8 KB, row-major [m][k], stride 32
  __shared__ u16 Bs[BN * BK];   // 8 KB, [n][k] (i.e. B^T), stride 32
  const int tid = threadIdx.x;
  const int wave = tid >> 6;
  const int lane = tid & 63;
  const int m0 = blockIdx.y * BM;
  const int n0 = blockIdx.x * BN;
  const int wr = wave >> 1;     // wave row 0..1
  const int wc = wave & 1;      // wave col 0..1
  const int quad = lane >> 4;   // 0..3
  const int l15 = lane & 15;

  f32x4 acc[4][4] = {};

  // staging geometry: per pass p (0/1), wave w stages 1 KB: rows p*64+w*16+lane/4,
  // 8 bf16 starting at col (lane&3)*8. LDS byte offset = p*4096 + w*1024 + lane*16.
  const int srow = wave * 16 + (lane >> 2);
  const int scol = (lane & 3) * 8;

  for (int kt = 0; kt < HH; kt += BK) {
    __syncthreads();   // previous iteration's LDS reads complete
#pragma unroll
    for (int p = 0; p < 2; ++p) {
      const u16* ga = Xb + (m0 + p * 64 + srow) * HH + kt + scol;
      const u16* gb = Wt + (n0 + p * 64 + srow) * HH + kt + scol;
      u16* la = As + p * 2048 + wave * 512;   // ushort units: 4096B=2048, 1024B=512
      u16* lb = Bs + p * 2048 + wave * 512;
      __builtin_amdgcn_global_load_lds(
          (const __attribute__((address_space(1))) unsigned int*)(unsigned long long)ga,
          (__attribute__((address_space(3))) unsigned int*)(unsigned long long)la, 16, 0, 0);
      __builtin_amdgcn_global_load_lds(
          (const __attribute__((address_space(1))) unsigned int*)(unsigned long long)gb,
          (__attribute__((address_space(3))) unsigned int*)(unsigned long long)lb, 16, 0, 0);
    }
    __syncthreads();   // drains vmcnt (global_load_lds) before LDS reads

    bf16x8 afr[4], bfr[4];
#pragma unroll
    for (int mi = 0; mi < 4; ++mi)
      afr[mi] = *(const bf16x8*)(As + (wr * 64 + mi * 16 + l15) * BK + quad * 8);
#pragma unroll
    for (int ni = 0; ni < 4; ++ni)
      bfr[ni] = *(const bf16x8*)(Bs + (wc * 64 + ni * 16 + l15) * BK + quad * 8);
#pragma unroll
    for (int mi = 0; mi < 4; ++mi)
#pragma unroll
      for (int ni = 0; ni < 4; ++ni)
        acc[mi][ni] = __builtin_amdgcn_mfma_f32_16x16x32_bf16(afr[mi], bfr[ni], acc[mi][ni], 0, 0, 0);
  }

  // epilogue: C/D layout col=lane&15, row=(lane>>4)*4+reg  [m89-verified]
#pragma unroll
  for (int mi = 0; mi < 4; ++mi)
#pragma unroll
    for (int ni = 0; ni < 4; ++ni) {
      int col = n0 + wc * 64 + ni * 16 + l15;
#pragma unroll
      for (int r = 0; r < 4; ++r) {
        int row = m0 + wr * 64 + mi * 16 + quad * 4 + r;
        QKV[row * QKVN + col] = f2bf(acc[mi][ni][r]);
      }
    }
}

// ---------------- attention: one wave per segment, online softmax ----------------
// Lane L owns output dim d=L for all 12 heads. Per edge: gather k row (bf16,
// coalesced), 12-reg butterfly reduce for per-head scores, online-softmax update.
__global__ __launch_bounds__(256) void attn_kernel(const u16* __restrict__ QKV,
                                                   const int* __restrict__ tailrow,
                                                   const int* __restrict__ offsets,
                                                   const int* __restrict__ counts,
                                                   float* __restrict__ out) {
  int seg = blockIdx.x * 4 + (threadIdx.x >> 6);
  int lane = threadIdx.x & 63;
  int start = offsets[seg];
  int cnt = counts[seg];

  const u16* qp = QKV + seg * QKVN + lane;
  float qv[NHEAD], m[NHEAD], l[NHEAD], oacc[NHEAD];
#pragma unroll
  for (int t = 0; t < NHEAD; ++t) {
    qv[t] = bf2f(qp[t * 64]) * 0.125f;   // fold 1/sqrt(64) into q
    m[t] = -__builtin_inff();
    l[t] = 0.f;
    oacc[t] = 0.f;
  }

  for (int e = 0; e < cnt; ++e) {
    int row = tailrow[start + e];               // wave-uniform
    const u16* kp = QKV + row * QKVN + HH + lane;
    const u16* vp = kp + HH;
    float sc[NHEAD];
#pragma unroll
    for (int t = 0; t < NHEAD; ++t) sc[t] = qv[t] * bf2f(kp[t * 64]);
    // butterfly sum over 64 lanes -> every lane holds all 12 head scores
#pragma unroll
    for (int off = 1; off < 64; off <<= 1) {
#pragma unroll
      for (int t = 0; t < NHEAD; ++t) sc[t] += __shfl_xor(sc[t], off, 64);
    }
#pragma unroll
    for (int t = 0; t < NHEAD; ++t) {
      float vvf = bf2f(vp[t * 64]);
      float mn = fmaxf(m[t], sc[t]);
      float al = __expf(m[t] - mn);   // exp(-inf)=0 on first edge
      float ex = __expf(sc[t] - mn);
      l[t] = l[t] * al + ex;
      oacc[t] = oacc[t] * al + ex * vvf;
      m[t] = mn;
    }
  }

  float* op = out + seg * HH + lane;
#pragma unroll
  for (int t = 0; t < NHEAD; ++t) op[t * 64] = oacc[t] / fmaxf(l[t], 1e-9f);
}

// ---------------- launch ----------------
extern "C" void kernel_launch(void* const* d_in, const int* in_sizes, int n_in,
                              void* d_out, int out_size, void* d_ws, size_t ws_size,
                              hipStream_t stream) {
  const float* X  = (const float*)d_in[0];
  const int*   EI = (const int*)d_in[1];
  const float* Wq = (const float*)d_in[2];
  const float* Wk = (const float*)d_in[3];
  const float* Wv = (const float*)d_in[4];
  float* out = (float*)d_out;
  const int E = in_sizes[1] / 4;

  // workspace layout
  char* ws = (char*)d_ws;
  int* counts  = (int*)(ws);                 // 32 KB
  int* cursor  = (int*)(ws + 32768);         // 32 KB
  int* offsets = (int*)(ws + 65536);         // 32 KB
  int* tailrow = (int*)(ws + 98304);         // E*4 = 512 KB
  u16* Xb      = (u16*)(ws + 622592);        // 8192*768*2  = 12.6 MB
  u16* Wt      = (u16*)(ws + 13205504);      // 2304*768*2  = 3.5 MB
  u16* QKV     = (u16*)(ws + 16744448);      // 8192*2304*2 = 37.7 MB  (total ~54.5 MB)

  hipMemsetAsync(counts, 0, 65536, stream);  // counts + cursor

  cast_x_kernel<<<(NSEG * HH / 4) / 256, 256, 0, stream>>>(X, Xb);
  transpose_w_kernel<<<dim3(QKVN / 32, HH / 32), dim3(32, 8), 0, stream>>>(Wq, Wk, Wv, Wt);
  count_kernel<<<(E + 255) / 256, 256, 0, stream>>>(EI, counts, E);
  scan_kernel<<<1, NSCAN, 0, stream>>>(counts, offsets);
  scatter_kernel<<<(E + 255) / 256, 256, 0, stream>>>(EI, offsets, cursor, tailrow, E);
  gemm_kernel<<<dim3(QKVN / BN, NSEG / BM), 256, 0, stream>>>(Xb, Wt, QKV);
  attn_kernel<<<NSEG / 4, 256, 0, stream>>>(QKV, tailrow, offsets, counts, out);
}

// Round 2
// 214.168 us; speedup vs baseline: 1.5938x; 1.5938x over previous
//
#include <hip/hip_runtime.h>

// Problem constants (fixed by reference)
#define BB 8
#define NN 1024
#define HH 768
#define NHEAD 12
#define HD 64
#define NSEG 8192            // B*N
#define QKVN 2304            // 3*H
#define NSCAN 1024           // scan block threads

typedef unsigned short u16;
typedef __attribute__((ext_vector_type(8))) short bf16x8;
typedef __attribute__((ext_vector_type(4))) float f32x4;

__device__ __forceinline__ float bf2f(u16 v) {
  return __uint_as_float(((unsigned)v) << 16);
}
__device__ __forceinline__ u16 f2bf(float f) {
  unsigned u = __float_as_uint(f);
  u += 0x7FFFu + ((u >> 16) & 1u);
  return (u16)(u >> 16);
}

// ---------------- prep: cast node_states fp32 -> bf16 ----------------
__global__ void cast_x_kernel(const float* __restrict__ X, u16* __restrict__ Xb) {
  int i = blockIdx.x * blockDim.x + threadIdx.x;   // one float4 per thread
  float4 f = ((const float4*)X)[i];
  ushort4 o;
  o.x = f2bf(f.x); o.y = f2bf(f.y); o.z = f2bf(f.z); o.w = f2bf(f.w);
  ((ushort4*)Xb)[i] = o;
}

// ------------- prep: build Wt[n][k] = Wsel[k][n] in bf16 -------------
// Wt is (2304 x 768): rows 0..767 = Wq^T, 768..1535 = Wk^T, 1536.. = Wv^T
__global__ void transpose_w_kernel(const float* __restrict__ Wq,
                                   const float* __restrict__ Wk,
                                   const float* __restrict__ Wv,
                                   u16* __restrict__ Wt) {
  __shared__ float tile[32][33];
  int n0 = blockIdx.x * 32;   // 0..2303 (output row / source col)
  int k0 = blockIdx.y * 32;   // 0..767
  const float* W = (n0 < HH) ? Wq : (n0 < 2 * HH ? Wk : Wv);
  int nb = n0 - (n0 < HH ? 0 : (n0 < 2 * HH ? HH : 2 * HH));
  int tx = threadIdx.x, ty = threadIdx.y;   // block (32, 8)
#pragma unroll
  for (int r = 0; r < 4; ++r)
    tile[ty + 8 * r][tx] = W[(k0 + ty + 8 * r) * HH + nb + tx];
  __syncthreads();
#pragma unroll
  for (int r = 0; r < 4; ++r)
    Wt[(n0 + ty + 8 * r) * HH + k0 + tx] = f2bf(tile[tx][ty + 8 * r]);
}

// ---------------- CSR build ----------------
__global__ void count_kernel(const int* __restrict__ EI, int* __restrict__ counts, int E) {
  int e = blockIdx.x * blockDim.x + threadIdx.x;
  if (e >= E) return;
  int seg = EI[e] * NN + EI[E + e];   // eb*N + ei
  atomicAdd(&counts[seg], 1);
}

__global__ void scan_kernel(const int* __restrict__ counts, int* __restrict__ offsets) {
  __shared__ int sdata[NSCAN];
  int t = threadIdx.x;
  int base = t * 8;
  int loc[8];
  int run = 0;
#pragma unroll
  for (int r = 0; r < 8; ++r) { loc[r] = run; run += counts[base + r]; }
  sdata[t] = run;
  __syncthreads();
  for (int off = 1; off < NSCAN; off <<= 1) {
    int v = (t >= off) ? sdata[t - off] : 0;
    __syncthreads();
    sdata[t] += v;
    __syncthreads();
  }
  int excl = sdata[t] - run;
#pragma unroll
  for (int r = 0; r < 8; ++r) offsets[base + r] = excl + loc[r];
}

__global__ void scatter_kernel(const int* __restrict__ EI,
                               const int* __restrict__ offsets,
                               int* __restrict__ cursor,
                               int* __restrict__ tailrow, int E) {
  int e = blockIdx.x * blockDim.x + threadIdx.x;
  if (e >= E) return;
  int b = EI[e];
  int seg = b * NN + EI[E + e];
  int j = EI[2 * E + e];
  int pos = atomicAdd(&cursor[seg], 1);
  tailrow[offsets[seg] + pos] = b * NN + j;
}

// ---------------- fused QKV GEMM: (8192x768) @ (768x2304), bf16 MFMA ----------------
#define BM 128
#define BN 128
#define BK 32

__global__ __launch_bounds__(256) void gemm_kernel(const u16* __restrict__ Xb,
                                                   const u16* __restrict__ Wt,
                                                   u16* __restrict__ QKV) {
  __shared__ u16 As[BM * BK];   // 8 KB, row-major [m][k], stride 32
  __shared__ u16 Bs[BN * BK];   // 8 KB, [n][k] (i.e. B^T), stride 32
  const int tid = threadIdx.x;
  const int wave = tid >> 6;
  const int lane = tid & 63;
  const int m0 = blockIdx.y * BM;
  const int n0 = blockIdx.x * BN;
  const int wr = wave >> 1;     // wave row 0..1
  const int wc = wave & 1;      // wave col 0..1
  const int quad = lane >> 4;   // 0..3
  const int l15 = lane & 15;

  f32x4 acc[4][4] = {};

  const int srow = wave * 16 + (lane >> 2);
  const int scol = (lane & 3) * 8;

  for (int kt = 0; kt < HH; kt += BK) {
    __syncthreads();   // previous iteration's LDS reads complete
#pragma unroll
    for (int p = 0; p < 2; ++p) {
      const u16* ga = Xb + (m0 + p * 64 + srow) * HH + kt + scol;
      const u16* gb = Wt + (n0 + p * 64 + srow) * HH + kt + scol;
      u16* la = As + p * 2048 + wave * 512;
      u16* lb = Bs + p * 2048 + wave * 512;
      __builtin_amdgcn_global_load_lds(
          (const __attribute__((address_space(1))) unsigned int*)(unsigned long long)ga,
          (__attribute__((address_space(3))) unsigned int*)(unsigned long long)la, 16, 0, 0);
      __builtin_amdgcn_global_load_lds(
          (const __attribute__((address_space(1))) unsigned int*)(unsigned long long)gb,
          (__attribute__((address_space(3))) unsigned int*)(unsigned long long)lb, 16, 0, 0);
    }
    __syncthreads();

    bf16x8 afr[4], bfr[4];
#pragma unroll
    for (int mi = 0; mi < 4; ++mi)
      afr[mi] = *(const bf16x8*)(As + (wr * 64 + mi * 16 + l15) * BK + quad * 8);
#pragma unroll
    for (int ni = 0; ni < 4; ++ni)
      bfr[ni] = *(const bf16x8*)(Bs + (wc * 64 + ni * 16 + l15) * BK + quad * 8);
#pragma unroll
    for (int mi = 0; mi < 4; ++mi)
#pragma unroll
      for (int ni = 0; ni < 4; ++ni)
        acc[mi][ni] = __builtin_amdgcn_mfma_f32_16x16x32_bf16(afr[mi], bfr[ni], acc[mi][ni], 0, 0, 0);
  }

  // epilogue: C/D layout col=lane&15, row=(lane>>4)*4+reg  [m89-verified]
#pragma unroll
  for (int mi = 0; mi < 4; ++mi)
#pragma unroll
    for (int ni = 0; ni < 4; ++ni) {
      int col = n0 + wc * 64 + ni * 16 + l15;
#pragma unroll
      for (int r = 0; r < 4; ++r) {
        int row = m0 + wr * 64 + mi * 16 + quad * 4 + r;
        QKV[row * QKVN + col] = f2bf(acc[mi][ni][r]);
      }
    }
}

// ---------------- attention: one wave per segment, online softmax ----------------
// Lane mapping chosen so reduction width == lanes-per-head:
//   part1: lane owns dims [8*lane, 8*lane+8)        -> heads 0..7,  head = lane>>3,
//          dot-reduce over 8 lanes (3 shuffle levels).
//   part2: lane owns dims [512+4*lane, 512+4*lane+4)-> heads 8..11, head = 8+(lane>>4),
//          dot-reduce over 16 lanes (4 shuffle levels).
// Per-head online-softmax state (m,l) lives redundantly in exactly the lanes
// owning that head's dims -> no broadcast needed. 7 shuffles/edge vs 72 before.
// K/V loads are 16B+8B vectors; next edge's loads are issued before processing
// the current edge (1-deep software pipeline).
__global__ __launch_bounds__(256) void attn_kernel(const u16* __restrict__ QKV,
                                                   const int* __restrict__ tailrow,
                                                   const int* __restrict__ offsets,
                                                   const int* __restrict__ counts,
                                                   float* __restrict__ out) {
  const int seg = blockIdx.x * 4 + (threadIdx.x >> 6);
  const int lane = threadIdx.x & 63;
  const int start = offsets[seg];
  const int cnt = counts[seg];

  // preload q (scaled by 1/sqrt(64))
  const u16* qrow = QKV + seg * QKVN;
  float qv1[8], qv2[4];
  {
    bf16x8 q1 = *(const bf16x8*)(qrow + lane * 8);
    ushort4 q2 = *(const ushort4*)(qrow + 512 + lane * 4);
#pragma unroll
    for (int i = 0; i < 8; ++i) qv1[i] = bf2f((u16)q1[i]) * 0.125f;
    qv2[0] = bf2f(q2.x) * 0.125f; qv2[1] = bf2f(q2.y) * 0.125f;
    qv2[2] = bf2f(q2.z) * 0.125f; qv2[3] = bf2f(q2.w) * 0.125f;
  }

  float m1 = -__builtin_inff(), l1 = 0.f;
  float m2 = -__builtin_inff(), l2 = 0.f;
  float o1[8] = {}, o2[4] = {};

  if (cnt > 0) {
    int row = tailrow[start];
    const u16* kp = QKV + row * QKVN + HH;
    bf16x8 k1n = *(const bf16x8*)(kp + lane * 8);
    ushort4 k2n = *(const ushort4*)(kp + 512 + lane * 4);
    bf16x8 v1n = *(const bf16x8*)(kp + HH + lane * 8);
    ushort4 v2n = *(const ushort4*)(kp + HH + 512 + lane * 4);

    for (int e = 0; e < cnt; ++e) {
      bf16x8 k1 = k1n; ushort4 k2 = k2n;
      bf16x8 v1 = v1n; ushort4 v2 = v2n;
      // prefetch next edge (re-load last edge on final iter: harmless)
      int nrow = tailrow[start + ((e + 1 < cnt) ? e + 1 : e)];
      const u16* nkp = QKV + nrow * QKVN + HH;
      k1n = *(const bf16x8*)(nkp + lane * 8);
      k2n = *(const ushort4*)(nkp + 512 + lane * 4);
      v1n = *(const bf16x8*)(nkp + HH + lane * 8);
      v2n = *(const ushort4*)(nkp + HH + 512 + lane * 4);

      // part-1 score (heads 0..7): reduce over 8-lane group
      float s1 = 0.f;
#pragma unroll
      for (int i = 0; i < 8; ++i) s1 += qv1[i] * bf2f((u16)k1[i]);
      s1 += __shfl_xor(s1, 1, 64);
      s1 += __shfl_xor(s1, 2, 64);
      s1 += __shfl_xor(s1, 4, 64);
      // part-2 score (heads 8..11): reduce over 16-lane group
      float s2 = qv2[0] * bf2f(k2.x) + qv2[1] * bf2f(k2.y) +
                 qv2[2] * bf2f(k2.z) + qv2[3] * bf2f(k2.w);
      s2 += __shfl_xor(s2, 1, 64);
      s2 += __shfl_xor(s2, 2, 64);
      s2 += __shfl_xor(s2, 4, 64);
      s2 += __shfl_xor(s2, 8, 64);

      // online softmax update, part 1
      {
        float mn = fmaxf(m1, s1);
        float al = __expf(m1 - mn);
        float ex = __expf(s1 - mn);
        l1 = l1 * al + ex;
#pragma unroll
        for (int i = 0; i < 8; ++i) o1[i] = o1[i] * al + ex * bf2f((u16)v1[i]);
        m1 = mn;
      }
      // online softmax update, part 2
      {
        float mn = fmaxf(m2, s2);
        float al = __expf(m2 - mn);
        float ex = __expf(s2 - mn);
        l2 = l2 * al + ex;
        o2[0] = o2[0] * al + ex * bf2f(v2.x);
        o2[1] = o2[1] * al + ex * bf2f(v2.y);
        o2[2] = o2[2] * al + ex * bf2f(v2.z);
        o2[3] = o2[3] * al + ex * bf2f(v2.w);
        m2 = mn;
      }
    }
  }

  const float inv1 = 1.f / fmaxf(l1, 1e-9f);
  const float inv2 = 1.f / fmaxf(l2, 1e-9f);
  float4 r0, r1c;
  r0.x = o1[0] * inv1; r0.y = o1[1] * inv1; r0.z = o1[2] * inv1; r0.w = o1[3] * inv1;
  r1c.x = o1[4] * inv1; r1c.y = o1[5] * inv1; r1c.z = o1[6] * inv1; r1c.w = o1[7] * inv1;
  float4 r2;
  r2.x = o2[0] * inv2; r2.y = o2[1] * inv2; r2.z = o2[2] * inv2; r2.w = o2[3] * inv2;
  float* op = out + seg * HH;
  ((float4*)(op + lane * 8))[0] = r0;
  ((float4*)(op + lane * 8))[1] = r1c;
  *(float4*)(op + 512 + lane * 4) = r2;
}

// ---------------- launch ----------------
extern "C" void kernel_launch(void* const* d_in, const int* in_sizes, int n_in,
                              void* d_out, int out_size, void* d_ws, size_t ws_size,
                              hipStream_t stream) {
  const float* X  = (const float*)d_in[0];
  const int*   EI = (const int*)d_in[1];
  const float* Wq = (const float*)d_in[2];
  const float* Wk = (const float*)d_in[3];
  const float* Wv = (const float*)d_in[4];
  float* out = (float*)d_out;
  const int E = in_sizes[1] / 4;

  // workspace layout
  char* ws = (char*)d_ws;
  int* counts  = (int*)(ws);                 // 32 KB
  int* cursor  = (int*)(ws + 32768);         // 32 KB
  int* offsets = (int*)(ws + 65536);         // 32 KB
  int* tailrow = (int*)(ws + 98304);         // E*4 = 512 KB
  u16* Xb      = (u16*)(ws + 622592);        // 8192*768*2  = 12.6 MB
  u16* Wt      = (u16*)(ws + 13205504);      // 2304*768*2  = 3.5 MB
  u16* QKV     = (u16*)(ws + 16744448);      // 8192*2304*2 = 37.7 MB

  hipMemsetAsync(counts, 0, 65536, stream);  // counts + cursor

  cast_x_kernel<<<(NSEG * HH / 4) / 256, 256, 0, stream>>>(X, Xb);
  transpose_w_kernel<<<dim3(QKVN / 32, HH / 32), dim3(32, 8), 0, stream>>>(Wq, Wk, Wv, Wt);
  count_kernel<<<(E + 255) / 256, 256, 0, stream>>>(EI, counts, E);
  scan_kernel<<<1, NSCAN, 0, stream>>>(counts, offsets);
  scatter_kernel<<<(E + 255) / 256, 256, 0, stream>>>(EI, offsets, cursor, tailrow, E);
  gemm_kernel<<<dim3(QKVN / BN, NSEG / BM), 256, 0, stream>>>(Xb, Wt, QKV);
  attn_kernel<<<NSEG / 4, 256, 0, stream>>>(QKV, tailrow, offsets, counts, out);
}

// Round 3
// 206.140 us; speedup vs baseline: 1.6559x; 1.0389x over previous
//
#include <hip/hip_runtime.h>

// Problem constants (fixed by reference)
#define BB 8
#define NN 1024
#define HH 768
#define NHEAD 12
#define HD 64
#define NSEG 8192            // B*N
#define QKVN 2304            // 3*H
#define MAXDEG 64            // bucket capacity per segment (Poisson(16); P(>64) ~ 1e-18)

typedef unsigned short u16;
typedef __attribute__((ext_vector_type(8))) short bf16x8;
typedef __attribute__((ext_vector_type(4))) float f32x4;

__device__ __forceinline__ float bf2f(u16 v) {
  return __uint_as_float(((unsigned)v) << 16);
}
__device__ __forceinline__ u16 f2bf(float f) {
  unsigned u = __float_as_uint(f);
  u += 0x7FFFu + ((u >> 16) & 1u);
  return (u16)(u >> 16);
}

// ---------------- prep: cast node_states fp32 -> bf16 ----------------
__global__ void cast_x_kernel(const float* __restrict__ X, u16* __restrict__ Xb) {
  int i = blockIdx.x * blockDim.x + threadIdx.x;   // one float4 per thread
  float4 f = ((const float4*)X)[i];
  ushort4 o;
  o.x = f2bf(f.x); o.y = f2bf(f.y); o.z = f2bf(f.z); o.w = f2bf(f.w);
  ((ushort4*)Xb)[i] = o;
}

// ------------- prep: build Wt[n][k] = Wsel[k][n] in bf16 -------------
// Wt is (2304 x 768): rows 0..767 = Wq^T, 768..1535 = Wk^T, 1536.. = Wv^T
__global__ void transpose_w_kernel(const float* __restrict__ Wq,
                                   const float* __restrict__ Wk,
                                   const float* __restrict__ Wv,
                                   u16* __restrict__ Wt) {
  __shared__ float tile[32][33];
  int n0 = blockIdx.x * 32;   // 0..2303 (output row / source col)
  int k0 = blockIdx.y * 32;   // 0..767
  const float* W = (n0 < HH) ? Wq : (n0 < 2 * HH ? Wk : Wv);
  int nb = n0 - (n0 < HH ? 0 : (n0 < 2 * HH ? HH : 2 * HH));
  int tx = threadIdx.x, ty = threadIdx.y;   // block (32, 8)
#pragma unroll
  for (int r = 0; r < 4; ++r)
    tile[ty + 8 * r][tx] = W[(k0 + ty + 8 * r) * HH + nb + tx];
  __syncthreads();
#pragma unroll
  for (int r = 0; r < 4; ++r)
    Wt[(n0 + ty + 8 * r) * HH + k0 + tx] = f2bf(tile[tx][ty + 8 * r]);
}

// ---------------- CSR build: single bucketed scatter ----------------
__global__ void build_kernel(const int* __restrict__ EI, int* __restrict__ cursor,
                             int* __restrict__ tailrow, int E) {
  int e = blockIdx.x * blockDim.x + threadIdx.x;
  if (e >= E) return;
  int b = EI[e];
  int seg = b * NN + EI[E + e];
  int j = EI[2 * E + e];
  int pos = atomicAdd(&cursor[seg], 1);
  if (pos < MAXDEG) tailrow[seg * MAXDEG + pos] = b * NN + j;
}

// ---------------- fused QKV GEMM: (8192x768) @ (768x2304), bf16 MFMA ----------------
#define BM 128
#define BN 128
#define BK 32

__global__ __launch_bounds__(256) void gemm_kernel(const u16* __restrict__ Xb,
                                                   const u16* __restrict__ Wt,
                                                   u16* __restrict__ QKV) {
  __shared__ u16 As[BM * BK];   // 8 KB, row-major [m][k], stride 32
  __shared__ u16 Bs[BN * BK];   // 8 KB, [n][k] (i.e. B^T), stride 32
  const int tid = threadIdx.x;
  const int wave = tid >> 6;
  const int lane = tid & 63;
  const int m0 = blockIdx.y * BM;
  const int n0 = blockIdx.x * BN;
  const int wr = wave >> 1;     // wave row 0..1
  const int wc = wave & 1;      // wave col 0..1
  const int quad = lane >> 4;   // 0..3
  const int l15 = lane & 15;

  f32x4 acc[4][4] = {};

  const int srow = wave * 16 + (lane >> 2);
  const int scol = (lane & 3) * 8;

  for (int kt = 0; kt < HH; kt += BK) {
    __syncthreads();   // previous iteration's LDS reads complete
#pragma unroll
    for (int p = 0; p < 2; ++p) {
      const u16* ga = Xb + (m0 + p * 64 + srow) * HH + kt + scol;
      const u16* gb = Wt + (n0 + p * 64 + srow) * HH + kt + scol;
      u16* la = As + p * 2048 + wave * 512;
      u16* lb = Bs + p * 2048 + wave * 512;
      __builtin_amdgcn_global_load_lds(
          (const __attribute__((address_space(1))) unsigned int*)(unsigned long long)ga,
          (__attribute__((address_space(3))) unsigned int*)(unsigned long long)la, 16, 0, 0);
      __builtin_amdgcn_global_load_lds(
          (const __attribute__((address_space(1))) unsigned int*)(unsigned long long)gb,
          (__attribute__((address_space(3))) unsigned int*)(unsigned long long)lb, 16, 0, 0);
    }
    __syncthreads();

    bf16x8 afr[4], bfr[4];
#pragma unroll
    for (int mi = 0; mi < 4; ++mi)
      afr[mi] = *(const bf16x8*)(As + (wr * 64 + mi * 16 + l15) * BK + quad * 8);
#pragma unroll
    for (int ni = 0; ni < 4; ++ni)
      bfr[ni] = *(const bf16x8*)(Bs + (wc * 64 + ni * 16 + l15) * BK + quad * 8);
#pragma unroll
    for (int mi = 0; mi < 4; ++mi)
#pragma unroll
      for (int ni = 0; ni < 4; ++ni)
        acc[mi][ni] = __builtin_amdgcn_mfma_f32_16x16x32_bf16(afr[mi], bfr[ni], acc[mi][ni], 0, 0, 0);
  }

  // epilogue: C/D layout col=lane&15, row=(lane>>4)*4+reg  [m89-verified]
#pragma unroll
  for (int mi = 0; mi < 4; ++mi)
#pragma unroll
    for (int ni = 0; ni < 4; ++ni) {
      int col = n0 + wc * 64 + ni * 16 + l15;
#pragma unroll
      for (int r = 0; r < 4; ++r) {
        int row = m0 + wr * 64 + mi * 16 + quad * 4 + r;
        QKV[row * QKVN + col] = f2bf(acc[mi][ni][r]);
      }
    }
}

// ---------------- attention: one wave per segment, 2-stream online softmax ----------------
// Lane mapping (R2-verified): lane owns dims [8L,8L+8) (heads 0..7, 8-lane
// reduce) + dims [512+4L,512+4L+4) (heads 8..11, 16-lane reduce).
// NEW: edges split into even/odd streams with independent (m,l,o) states,
// merged at the end -> 2x ILP on the serial online-softmax chain. 1-pair-deep
// data prefetch retained.
__global__ __launch_bounds__(256) void attn_kernel(const u16* __restrict__ QKV,
                                                   const int* __restrict__ tailrow,
                                                   const int* __restrict__ cursor,
                                                   float* __restrict__ out) {
  const int seg = blockIdx.x * 4 + (threadIdx.x >> 6);
  const int lane = threadIdx.x & 63;
  const int base = seg * MAXDEG;
  int cnt = cursor[seg];
  if (cnt > MAXDEG) cnt = MAXDEG;

  // preload q (scaled by 1/sqrt(64))
  const u16* qrow = QKV + seg * QKVN;
  float qv1[8], qv2[4];
  {
    bf16x8 q1 = *(const bf16x8*)(qrow + lane * 8);
    ushort4 q2 = *(const ushort4*)(qrow + 512 + lane * 4);
#pragma unroll
    for (int i = 0; i < 8; ++i) qv1[i] = bf2f((u16)q1[i]) * 0.125f;
    qv2[0] = bf2f(q2.x) * 0.125f; qv2[1] = bf2f(q2.y) * 0.125f;
    qv2[2] = bf2f(q2.z) * 0.125f; qv2[3] = bf2f(q2.w) * 0.125f;
  }

  // stream A and B states (part1 = heads 0..7, part2 = heads 8..11)
  float mA1 = -__builtin_inff(), lA1 = 0.f, mA2 = -__builtin_inff(), lA2 = 0.f;
  float mB1 = -__builtin_inff(), lB1 = 0.f, mB2 = -__builtin_inff(), lB2 = 0.f;
  float oA1[8] = {}, oA2[4] = {}, oB1[8] = {}, oB2[4] = {};

  auto loadkv = [&](int row, bf16x8& k1, ushort4& k2, bf16x8& v1, ushort4& v2) {
    const u16* kp = QKV + row * QKVN + HH;
    k1 = *(const bf16x8*)(kp + lane * 8);
    k2 = *(const ushort4*)(kp + 512 + lane * 4);
    v1 = *(const bf16x8*)(kp + HH + lane * 8);
    v2 = *(const ushort4*)(kp + HH + 512 + lane * 4);
  };

  auto process = [&](bf16x8 k1, ushort4 k2, bf16x8 v1, ushort4 v2,
                     float& m1, float& l1, float* o1,
                     float& m2, float& l2, float* o2) {
    float s1 = 0.f;
#pragma unroll
    for (int i = 0; i < 8; ++i) s1 += qv1[i] * bf2f((u16)k1[i]);
    s1 += __shfl_xor(s1, 1, 64);
    s1 += __shfl_xor(s1, 2, 64);
    s1 += __shfl_xor(s1, 4, 64);
    float s2 = qv2[0] * bf2f(k2.x) + qv2[1] * bf2f(k2.y) +
               qv2[2] * bf2f(k2.z) + qv2[3] * bf2f(k2.w);
    s2 += __shfl_xor(s2, 1, 64);
    s2 += __shfl_xor(s2, 2, 64);
    s2 += __shfl_xor(s2, 4, 64);
    s2 += __shfl_xor(s2, 8, 64);
    {
      float mn = fmaxf(m1, s1);
      float al = __expf(m1 - mn);
      float ex = __expf(s1 - mn);
      l1 = l1 * al + ex;
#pragma unroll
      for (int i = 0; i < 8; ++i) o1[i] = o1[i] * al + ex * bf2f((u16)v1[i]);
      m1 = mn;
    }
    {
      float mn = fmaxf(m2, s2);
      float al = __expf(m2 - mn);
      float ex = __expf(s2 - mn);
      l2 = l2 * al + ex;
      o2[0] = o2[0] * al + ex * bf2f(v2.x);
      o2[1] = o2[1] * al + ex * bf2f(v2.y);
      o2[2] = o2[2] * al + ex * bf2f(v2.z);
      o2[3] = o2[3] * al + ex * bf2f(v2.w);
      m2 = mn;
    }
  };

  if (cnt >= 2) {
    bf16x8 k1A, v1A, k1B, v1B, nk1A, nv1A, nk1B, nv1B;
    ushort4 k2A, v2A, k2B, v2B, nk2A, nv2A, nk2B, nv2B;
    loadkv(tailrow[base], k1A, k2A, v1A, v2A);
    loadkv(tailrow[base + 1], k1B, k2B, v1B, v2B);
    const int npair = cnt >> 1;
    for (int p = 0; p < npair; ++p) {
      int i2 = 2 * p + 2;
      int ia = (i2 < cnt) ? i2 : 0;               // odd-cnt: last iter loads edge cnt-1
      int ib = (i2 + 1 < cnt) ? i2 + 1 : ia;
      loadkv(tailrow[base + ia], nk1A, nk2A, nv1A, nv2A);
      loadkv(tailrow[base + ib], nk1B, nk2B, nv1B, nv2B);
      process(k1A, k2A, v1A, v2A, mA1, lA1, oA1, mA2, lA2, oA2);
      process(k1B, k2B, v1B, v2B, mB1, lB1, oB1, mB2, lB2, oB2);
      k1A = nk1A; k2A = nk2A; v1A = nv1A; v2A = nv2A;
      k1B = nk1B; k2B = nk2B; v1B = nv1B; v2B = nv2B;
    }
    if (cnt & 1)   // curA holds edge cnt-1 via the clamped prefetch
      process(k1A, k2A, v1A, v2A, mA1, lA1, oA1, mA2, lA2, oA2);
  } else if (cnt == 1) {
    bf16x8 k1A, v1A; ushort4 k2A, v2A;
    loadkv(tailrow[base], k1A, k2A, v1A, v2A);
    process(k1A, k2A, v1A, v2A, mA1, lA1, oA1, mA2, lA2, oA2);
  }

  // merge streams (−1e30 floor makes cnt==0 produce exact zeros, no NaN)
  float res1[8], res2[4];
  {
    float mn = fmaxf(fmaxf(mA1, mB1), -1e30f);
    float aA = __expf(mA1 - mn), aB = __expf(mB1 - mn);
    float l = lA1 * aA + lB1 * aB;
    float inv = 1.f / fmaxf(l, 1e-9f);
#pragma unroll
    for (int i = 0; i < 8; ++i) res1[i] = (oA1[i] * aA + oB1[i] * aB) * inv;
  }
  {
    float mn = fmaxf(fmaxf(mA2, mB2), -1e30f);
    float aA = __expf(mA2 - mn), aB = __expf(mB2 - mn);
    float l = lA2 * aA + lB2 * aB;
    float inv = 1.f / fmaxf(l, 1e-9f);
#pragma unroll
    for (int i = 0; i < 4; ++i) res2[i] = (oA2[i] * aA + oB2[i] * aB) * inv;
  }

  float* op = out + seg * HH;
  float4 r0 = {res1[0], res1[1], res1[2], res1[3]};
  float4 r1 = {res1[4], res1[5], res1[6], res1[7]};
  float4 r2 = {res2[0], res2[1], res2[2], res2[3]};
  ((float4*)(op + lane * 8))[0] = r0;
  ((float4*)(op + lane * 8))[1] = r1;
  *(float4*)(op + 512 + lane * 4) = r2;
}

// ---------------- launch ----------------
extern "C" void kernel_launch(void* const* d_in, const int* in_sizes, int n_in,
                              void* d_out, int out_size, void* d_ws, size_t ws_size,
                              hipStream_t stream) {
  const float* X  = (const float*)d_in[0];
  const int*   EI = (const int*)d_in[1];
  const float* Wq = (const float*)d_in[2];
  const float* Wk = (const float*)d_in[3];
  const float* Wv = (const float*)d_in[4];
  float* out = (float*)d_out;
  const int E = in_sizes[1] / 4;

  // workspace layout (~56 MB)
  char* ws = (char*)d_ws;
  int* cursor  = (int*)(ws);                 // 32 KB
  int* tailrow = (int*)(ws + 32768);         // NSEG*64*4 = 2 MB
  u16* Xb      = (u16*)(ws + 2129920);       // 8192*768*2  = 12.6 MB
  u16* Wt      = (u16*)(ws + 14712832);      // 2304*768*2  = 3.5 MB
  u16* QKV     = (u16*)(ws + 18251776);      // 8192*2304*2 = 37.7 MB

  hipMemsetAsync(cursor, 0, NSEG * 4, stream);

  cast_x_kernel<<<(NSEG * HH / 4) / 256, 256, 0, stream>>>(X, Xb);
  transpose_w_kernel<<<dim3(QKVN / 32, HH / 32), dim3(32, 8), 0, stream>>>(Wq, Wk, Wv, Wt);
  build_kernel<<<(E + 255) / 256, 256, 0, stream>>>(EI, cursor, tailrow, E);
  gemm_kernel<<<dim3(QKVN / BN, NSEG / BM), 256, 0, stream>>>(Xb, Wt, QKV);
  attn_kernel<<<NSEG / 4, 256, 0, stream>>>(QKV, tailrow, cursor, out);
}

// Round 4
// 191.523 us; speedup vs baseline: 1.7823x; 1.0763x over previous
//
#include <hip/hip_runtime.h>

// Problem constants (fixed by reference)
#define BB 8
#define NN 1024
#define HH 768
#define NHEAD 12
#define HD 64
#define NSEG 8192            // B*N
#define QKVN 2304            // 3*H
#define MAXDEG 64            // bucket capacity per segment (Poisson(16); P(>64) ~ 1e-18)

typedef unsigned short u16;
typedef __attribute__((ext_vector_type(8))) short bf16x8;
typedef __attribute__((ext_vector_type(4))) float f32x4;

__device__ __forceinline__ float bf2f(u16 v) {
  return __uint_as_float(((unsigned)v) << 16);
}
__device__ __forceinline__ u16 f2bf(float f) {
  unsigned u = __float_as_uint(f);
  u += 0x7FFFu + ((u >> 16) & 1u);
  return (u16)(u >> 16);
}

// ---------------- prep: cast node_states fp32 -> bf16 ----------------
__global__ void cast_x_kernel(const float* __restrict__ X, u16* __restrict__ Xb) {
  int i = blockIdx.x * blockDim.x + threadIdx.x;   // one float4 per thread
  float4 f = ((const float4*)X)[i];
  ushort4 o;
  o.x = f2bf(f.x); o.y = f2bf(f.y); o.z = f2bf(f.z); o.w = f2bf(f.w);
  ((ushort4*)Xb)[i] = o;
}

// ------------- prep: build Wt[n][k] = Wsel[k][n] in bf16 -------------
__global__ void transpose_w_kernel(const float* __restrict__ Wq,
                                   const float* __restrict__ Wk,
                                   const float* __restrict__ Wv,
                                   u16* __restrict__ Wt) {
  __shared__ float tile[32][33];
  int n0 = blockIdx.x * 32;
  int k0 = blockIdx.y * 32;
  const float* W = (n0 < HH) ? Wq : (n0 < 2 * HH ? Wk : Wv);
  int nb = n0 - (n0 < HH ? 0 : (n0 < 2 * HH ? HH : 2 * HH));
  int tx = threadIdx.x, ty = threadIdx.y;   // block (32, 8)
#pragma unroll
  for (int r = 0; r < 4; ++r)
    tile[ty + 8 * r][tx] = W[(k0 + ty + 8 * r) * HH + nb + tx];
  __syncthreads();
#pragma unroll
  for (int r = 0; r < 4; ++r)
    Wt[(n0 + ty + 8 * r) * HH + k0 + tx] = f2bf(tile[tx][ty + 8 * r]);
}

// ---------------- CSR build: single bucketed scatter ----------------
__global__ void build_kernel(const int* __restrict__ EI, int* __restrict__ cursor,
                             int* __restrict__ tailrow, int E) {
  int e = blockIdx.x * blockDim.x + threadIdx.x;
  if (e >= E) return;
  int b = EI[e];
  int seg = b * NN + EI[E + e];
  int j = EI[2 * E + e];
  int pos = atomicAdd(&cursor[seg], 1);
  if (pos < MAXDEG) tailrow[seg * MAXDEG + pos] = b * NN + j;
}

// ---------------- fused QKV GEMM: (8192x768) @ (768x2304), bf16 MFMA ----------------
#define BM 128
#define BN 128
#define BK 32

__global__ __launch_bounds__(256) void gemm_kernel(const u16* __restrict__ Xb,
                                                   const u16* __restrict__ Wt,
                                                   u16* __restrict__ QKV) {
  __shared__ u16 As[BM * BK];
  __shared__ u16 Bs[BN * BK];
  const int tid = threadIdx.x;
  const int wave = tid >> 6;
  const int lane = tid & 63;
  const int m0 = blockIdx.y * BM;
  const int n0 = blockIdx.x * BN;
  const int wr = wave >> 1;
  const int wc = wave & 1;
  const int quad = lane >> 4;
  const int l15 = lane & 15;

  f32x4 acc[4][4] = {};

  const int srow = wave * 16 + (lane >> 2);
  const int scol = (lane & 3) * 8;

  for (int kt = 0; kt < HH; kt += BK) {
    __syncthreads();
#pragma unroll
    for (int p = 0; p < 2; ++p) {
      const u16* ga = Xb + (m0 + p * 64 + srow) * HH + kt + scol;
      const u16* gb = Wt + (n0 + p * 64 + srow) * HH + kt + scol;
      u16* la = As + p * 2048 + wave * 512;
      u16* lb = Bs + p * 2048 + wave * 512;
      __builtin_amdgcn_global_load_lds(
          (const __attribute__((address_space(1))) unsigned int*)(unsigned long long)ga,
          (__attribute__((address_space(3))) unsigned int*)(unsigned long long)la, 16, 0, 0);
      __builtin_amdgcn_global_load_lds(
          (const __attribute__((address_space(1))) unsigned int*)(unsigned long long)gb,
          (__attribute__((address_space(3))) unsigned int*)(unsigned long long)lb, 16, 0, 0);
    }
    __syncthreads();

    bf16x8 afr[4], bfr[4];
#pragma unroll
    for (int mi = 0; mi < 4; ++mi)
      afr[mi] = *(const bf16x8*)(As + (wr * 64 + mi * 16 + l15) * BK + quad * 8);
#pragma unroll
    for (int ni = 0; ni < 4; ++ni)
      bfr[ni] = *(const bf16x8*)(Bs + (wc * 64 + ni * 16 + l15) * BK + quad * 8);
#pragma unroll
    for (int mi = 0; mi < 4; ++mi)
#pragma unroll
      for (int ni = 0; ni < 4; ++ni)
        acc[mi][ni] = __builtin_amdgcn_mfma_f32_16x16x32_bf16(afr[mi], bfr[ni], acc[mi][ni], 0, 0, 0);
  }

#pragma unroll
  for (int mi = 0; mi < 4; ++mi)
#pragma unroll
    for (int ni = 0; ni < 4; ++ni) {
      int col = n0 + wc * 64 + ni * 16 + l15;
#pragma unroll
      for (int r = 0; r < 4; ++r) {
        int row = m0 + wr * 64 + mi * 16 + quad * 4 + r;
        QKV[row * QKVN + col] = f2bf(acc[mi][ni][r]);
      }
    }
}

// ---------------- attention: TWO waves per segment, LDS merge ----------------
// Lane mapping (R2-verified): lane owns dims [8L,8L+8) (heads 0..7, 8-lane
// reduce) + dims [512+4L,512+4L+4) (heads 8..11, 16-lane reduce).
// R4: segment's edge list split stride-2 across 2 waves (halves serial chain
// AND straggler tail, doubles latency-hiding wave count). Single-stream state
// per wave (R3 lesson: in-wave ILP costs occupancy for nothing). Odd wave
// publishes (m,l,o) via state-major LDS (conflict-free), even wave merges.
__global__ __launch_bounds__(256) void attn_kernel(const u16* __restrict__ QKV,
                                                   const int* __restrict__ tailrow,
                                                   const int* __restrict__ cursor,
                                                   float* __restrict__ out) {
  __shared__ float sm[2 * 16 * 64];   // [seg-in-block][16 states][64 lanes] = 8 KB
  const int wv = threadIdx.x >> 6;    // 0..3
  const int lane = threadIdx.x & 63;
  const int sIb = wv >> 1;            // segment within block
  const int half = wv & 1;            // which half of the edge list
  const int seg = blockIdx.x * 2 + sIb;
  const int base = seg * MAXDEG;
  int cnt = cursor[seg];
  if (cnt > MAXDEG) cnt = MAXDEG;
  const int myn = (cnt > half) ? ((cnt - half + 1) >> 1) : 0;   // edges at half, half+2, ...

  // preload q (scaled by 1/sqrt(64))
  const u16* qrow = QKV + seg * QKVN;
  float qv1[8], qv2[4];
  {
    bf16x8 q1 = *(const bf16x8*)(qrow + lane * 8);
    ushort4 q2 = *(const ushort4*)(qrow + 512 + lane * 4);
#pragma unroll
    for (int i = 0; i < 8; ++i) qv1[i] = bf2f((u16)q1[i]) * 0.125f;
    qv2[0] = bf2f(q2.x) * 0.125f; qv2[1] = bf2f(q2.y) * 0.125f;
    qv2[2] = bf2f(q2.z) * 0.125f; qv2[3] = bf2f(q2.w) * 0.125f;
  }

  float m1 = -__builtin_inff(), l1 = 0.f;
  float m2 = -__builtin_inff(), l2 = 0.f;
  float o1[8] = {}, o2[4] = {};

  auto loadkv = [&](int row, bf16x8& k1, ushort4& k2, bf16x8& v1, ushort4& v2) {
    const u16* kp = QKV + row * QKVN + HH;
    k1 = *(const bf16x8*)(kp + lane * 8);
    k2 = *(const ushort4*)(kp + 512 + lane * 4);
    v1 = *(const bf16x8*)(kp + HH + lane * 8);
    v2 = *(const ushort4*)(kp + HH + 512 + lane * 4);
  };

  if (myn > 0) {
    bf16x8 k1, v1, k1n, v1n;
    ushort4 k2, v2, k2n, v2n;
    loadkv(tailrow[base + half], k1, k2, v1, v2);
    for (int t = 0; t < myn; ++t) {
      int tn = (t + 1 < myn) ? t + 1 : t;   // clamp: harmless reload on last iter
      loadkv(tailrow[base + half + 2 * tn], k1n, k2n, v1n, v2n);

      float s1 = 0.f;
#pragma unroll
      for (int i = 0; i < 8; ++i) s1 += qv1[i] * bf2f((u16)k1[i]);
      s1 += __shfl_xor(s1, 1, 64);
      s1 += __shfl_xor(s1, 2, 64);
      s1 += __shfl_xor(s1, 4, 64);
      float s2 = qv2[0] * bf2f(k2.x) + qv2[1] * bf2f(k2.y) +
                 qv2[2] * bf2f(k2.z) + qv2[3] * bf2f(k2.w);
      s2 += __shfl_xor(s2, 1, 64);
      s2 += __shfl_xor(s2, 2, 64);
      s2 += __shfl_xor(s2, 4, 64);
      s2 += __shfl_xor(s2, 8, 64);

      {
        float mn = fmaxf(m1, s1);
        float al = __expf(m1 - mn);
        float ex = __expf(s1 - mn);
        l1 = l1 * al + ex;
#pragma unroll
        for (int i = 0; i < 8; ++i) o1[i] = o1[i] * al + ex * bf2f((u16)v1[i]);
        m1 = mn;
      }
      {
        float mn = fmaxf(m2, s2);
        float al = __expf(m2 - mn);
        float ex = __expf(s2 - mn);
        l2 = l2 * al + ex;
        o2[0] = o2[0] * al + ex * bf2f(v2.x);
        o2[1] = o2[1] * al + ex * bf2f(v2.y);
        o2[2] = o2[2] * al + ex * bf2f(v2.z);
        o2[3] = o2[3] * al + ex * bf2f(v2.w);
        m2 = mn;
      }
      k1 = k1n; k2 = k2n; v1 = v1n; v2 = v2n;
    }
  }

  // odd wave publishes its state (state-major: lane-contiguous, conflict-free)
  float* sb = sm + sIb * 16 * 64;
  if (half == 1) {
    sb[0 * 64 + lane] = m1;  sb[1 * 64 + lane] = l1;
    sb[2 * 64 + lane] = m2;  sb[3 * 64 + lane] = l2;
#pragma unroll
    for (int i = 0; i < 8; ++i) sb[(4 + i) * 64 + lane] = o1[i];
#pragma unroll
    for (int i = 0; i < 4; ++i) sb[(12 + i) * 64 + lane] = o2[i];
  }
  __syncthreads();
  if (half == 0) {
    float mB1 = sb[0 * 64 + lane], lB1 = sb[1 * 64 + lane];
    float mB2 = sb[2 * 64 + lane], lB2 = sb[3 * 64 + lane];

    float res1[8], res2[4];
    {
      float mn = fmaxf(fmaxf(m1, mB1), -1e30f);
      float aA = __expf(m1 - mn), aB = __expf(mB1 - mn);
      float l = l1 * aA + lB1 * aB;
      float inv = 1.f / fmaxf(l, 1e-9f);
#pragma unroll
      for (int i = 0; i < 8; ++i)
        res1[i] = (o1[i] * aA + sb[(4 + i) * 64 + lane] * aB) * inv;
    }
    {
      float mn = fmaxf(fmaxf(m2, mB2), -1e30f);
      float aA = __expf(m2 - mn), aB = __expf(mB2 - mn);
      float l = l2 * aA + lB2 * aB;
      float inv = 1.f / fmaxf(l, 1e-9f);
#pragma unroll
      for (int i = 0; i < 4; ++i)
        res2[i] = (o2[i] * aA + sb[(12 + i) * 64 + lane] * aB) * inv;
    }

    float* op = out + seg * HH;
    float4 r0 = {res1[0], res1[1], res1[2], res1[3]};
    float4 r1 = {res1[4], res1[5], res1[6], res1[7]};
    float4 r2 = {res2[0], res2[1], res2[2], res2[3]};
    ((float4*)(op + lane * 8))[0] = r0;
    ((float4*)(op + lane * 8))[1] = r1;
    *(float4*)(op + 512 + lane * 4) = r2;
  }
}

// ---------------- launch ----------------
extern "C" void kernel_launch(void* const* d_in, const int* in_sizes, int n_in,
                              void* d_out, int out_size, void* d_ws, size_t ws_size,
                              hipStream_t stream) {
  const float* X  = (const float*)d_in[0];
  const int*   EI = (const int*)d_in[1];
  const float* Wq = (const float*)d_in[2];
  const float* Wk = (const float*)d_in[3];
  const float* Wv = (const float*)d_in[4];
  float* out = (float*)d_out;
  const int E = in_sizes[1] / 4;

  // workspace layout (~56 MB)
  char* ws = (char*)d_ws;
  int* cursor  = (int*)(ws);                 // 32 KB
  int* tailrow = (int*)(ws + 32768);         // NSEG*64*4 = 2 MB
  u16* Xb      = (u16*)(ws + 2129920);       // 8192*768*2  = 12.6 MB
  u16* Wt      = (u16*)(ws + 14712832);      // 2304*768*2  = 3.5 MB
  u16* QKV     = (u16*)(ws + 18251776);      // 8192*2304*2 = 37.7 MB

  hipMemsetAsync(cursor, 0, NSEG * 4, stream);

  cast_x_kernel<<<(NSEG * HH / 4) / 256, 256, 0, stream>>>(X, Xb);
  transpose_w_kernel<<<dim3(QKVN / 32, HH / 32), dim3(32, 8), 0, stream>>>(Wq, Wk, Wv, Wt);
  build_kernel<<<(E + 255) / 256, 256, 0, stream>>>(EI, cursor, tailrow, E);
  gemm_kernel<<<dim3(QKVN / BN, NSEG / BM), 256, 0, stream>>>(Xb, Wt, QKV);
  attn_kernel<<<NSEG / 2, 256, 0, stream>>>(QKV, tailrow, cursor, out);
}

// Round 5
// 187.893 us; speedup vs baseline: 1.8167x; 1.0193x over previous
//
#include <hip/hip_runtime.h>

// Problem constants (fixed by reference)
#define BB 8
#define NN 1024
#define HH 768
#define NHEAD 12
#define HD 64
#define NSEG 8192            // B*N
#define QKVN 2304            // 3*H
#define MAXDEG 64            // bucket capacity per segment (Poisson(16); P(>64) ~ 1e-18)

typedef unsigned short u16;
typedef __attribute__((ext_vector_type(8))) short bf16x8;
typedef __attribute__((ext_vector_type(4))) float f32x4;

__device__ __forceinline__ float bf2f(u16 v) {
  return __uint_as_float(((unsigned)v) << 16);
}
__device__ __forceinline__ u16 f2bf(float f) {
  unsigned u = __float_as_uint(f);
  u += 0x7FFFu + ((u >> 16) & 1u);
  return (u16)(u >> 16);
}

// ---------------- prep: cast node_states fp32 -> bf16 ----------------
__global__ void cast_x_kernel(const float* __restrict__ X, u16* __restrict__ Xb) {
  int i = blockIdx.x * blockDim.x + threadIdx.x;   // one float4 per thread
  float4 f = ((const float4*)X)[i];
  ushort4 o;
  o.x = f2bf(f.x); o.y = f2bf(f.y); o.z = f2bf(f.z); o.w = f2bf(f.w);
  ((ushort4*)Xb)[i] = o;
}

// ------------- prep: build Wt[n][k] = Wsel[k][n] in bf16 -------------
__global__ void transpose_w_kernel(const float* __restrict__ Wq,
                                   const float* __restrict__ Wk,
                                   const float* __restrict__ Wv,
                                   u16* __restrict__ Wt) {
  __shared__ float tile[32][33];
  int n0 = blockIdx.x * 32;
  int k0 = blockIdx.y * 32;
  const float* W = (n0 < HH) ? Wq : (n0 < 2 * HH ? Wk : Wv);
  int nb = n0 - (n0 < HH ? 0 : (n0 < 2 * HH ? HH : 2 * HH));
  int tx = threadIdx.x, ty = threadIdx.y;   // block (32, 8)
#pragma unroll
  for (int r = 0; r < 4; ++r)
    tile[ty + 8 * r][tx] = W[(k0 + ty + 8 * r) * HH + nb + tx];
  __syncthreads();
#pragma unroll
  for (int r = 0; r < 4; ++r)
    Wt[(n0 + ty + 8 * r) * HH + k0 + tx] = f2bf(tile[tx][ty + 8 * r]);
}

// ---------------- CSR build: single bucketed scatter ----------------
__global__ void build_kernel(const int* __restrict__ EI, int* __restrict__ cursor,
                             int* __restrict__ tailrow, int E) {
  int e = blockIdx.x * blockDim.x + threadIdx.x;
  if (e >= E) return;
  int b = EI[e];
  int seg = b * NN + EI[E + e];
  int j = EI[2 * E + e];
  int pos = atomicAdd(&cursor[seg], 1);
  if (pos < MAXDEG) tailrow[seg * MAXDEG + pos] = b * NN + j;
}

// ---------------- fused QKV GEMM: (8192x768) @ (768x2304), bf16 MFMA ----------------
// R5: double-buffered LDS (BK=32, ONE barrier per iter). Staging of tile k+1
// is issued right after the barrier, before the ds_reads of tile k, so the
// vmcnt drain at the next barrier waits on loads a full iteration old.
#define BM 128
#define BN 128
#define BK 32

__global__ __launch_bounds__(256) void gemm_kernel(const u16* __restrict__ Xb,
                                                   const u16* __restrict__ Wt,
                                                   u16* __restrict__ QKV) {
  __shared__ u16 As[2][BM * BK];   // 2 x 8 KB
  __shared__ u16 Bs[2][BN * BK];   // 2 x 8 KB
  const int tid = threadIdx.x;
  const int wave = tid >> 6;
  const int lane = tid & 63;
  const int m0 = blockIdx.y * BM;
  const int n0 = blockIdx.x * BN;
  const int wr = wave >> 1;
  const int wc = wave & 1;
  const int quad = lane >> 4;
  const int l15 = lane & 15;

  f32x4 acc[4][4] = {};

  const int srow = wave * 16 + (lane >> 2);
  const int scol = (lane & 3) * 8;

  auto stage = [&](int buf, int kt) {
#pragma unroll
    for (int p = 0; p < 2; ++p) {
      const u16* ga = Xb + (m0 + p * 64 + srow) * HH + kt + scol;
      const u16* gb = Wt + (n0 + p * 64 + srow) * HH + kt + scol;
      u16* la = As[buf] + p * 2048 + wave * 512;
      u16* lb = Bs[buf] + p * 2048 + wave * 512;
      __builtin_amdgcn_global_load_lds(
          (const __attribute__((address_space(1))) unsigned int*)(unsigned long long)ga,
          (__attribute__((address_space(3))) unsigned int*)(unsigned long long)la, 16, 0, 0);
      __builtin_amdgcn_global_load_lds(
          (const __attribute__((address_space(1))) unsigned int*)(unsigned long long)gb,
          (__attribute__((address_space(3))) unsigned int*)(unsigned long long)lb, 16, 0, 0);
    }
  };

  stage(0, 0);
  int buf = 0;
  for (int kt = 0; kt < HH; kt += BK) {
    // One barrier per iter: guarantees (a) my+everyone's staging of `buf`
    // (issued last iter) has landed [vmcnt drain], (b) everyone's ds_reads of
    // buf^1 (last iter's compute) are done so we may overwrite it.
    __syncthreads();
    if (kt + BK < HH) stage(buf ^ 1, kt + BK);   // prefetch next tile, no wait

    bf16x8 afr[4], bfr[4];
#pragma unroll
    for (int mi = 0; mi < 4; ++mi)
      afr[mi] = *(const bf16x8*)(As[buf] + (wr * 64 + mi * 16 + l15) * BK + quad * 8);
#pragma unroll
    for (int ni = 0; ni < 4; ++ni)
      bfr[ni] = *(const bf16x8*)(Bs[buf] + (wc * 64 + ni * 16 + l15) * BK + quad * 8);
#pragma unroll
    for (int mi = 0; mi < 4; ++mi)
#pragma unroll
      for (int ni = 0; ni < 4; ++ni)
        acc[mi][ni] = __builtin_amdgcn_mfma_f32_16x16x32_bf16(afr[mi], bfr[ni], acc[mi][ni], 0, 0, 0);
    buf ^= 1;
  }

  // epilogue: C/D layout col=lane&15, row=(lane>>4)*4+reg  [m89-verified]
#pragma unroll
  for (int mi = 0; mi < 4; ++mi)
#pragma unroll
    for (int ni = 0; ni < 4; ++ni) {
      int col = n0 + wc * 64 + ni * 16 + l15;
#pragma unroll
      for (int r = 0; r < 4; ++r) {
        int row = m0 + wr * 64 + mi * 16 + quad * 4 + r;
        QKV[row * QKVN + col] = f2bf(acc[mi][ni][r]);
      }
    }
}

// ---------------- attention: TWO waves per segment, LDS merge ----------------
// (unchanged from R4 — 52.8 µs, likely near L2/L3 gather-delivery limit)
__global__ __launch_bounds__(256) void attn_kernel(const u16* __restrict__ QKV,
                                                   const int* __restrict__ tailrow,
                                                   const int* __restrict__ cursor,
                                                   float* __restrict__ out) {
  __shared__ float sm[2 * 16 * 64];   // [seg-in-block][16 states][64 lanes] = 8 KB
  const int wv = threadIdx.x >> 6;    // 0..3
  const int lane = threadIdx.x & 63;
  const int sIb = wv >> 1;            // segment within block
  const int half = wv & 1;            // which half of the edge list
  const int seg = blockIdx.x * 2 + sIb;
  const int base = seg * MAXDEG;
  int cnt = cursor[seg];
  if (cnt > MAXDEG) cnt = MAXDEG;
  const int myn = (cnt > half) ? ((cnt - half + 1) >> 1) : 0;   // edges at half, half+2, ...

  // preload q (scaled by 1/sqrt(64))
  const u16* qrow = QKV + seg * QKVN;
  float qv1[8], qv2[4];
  {
    bf16x8 q1 = *(const bf16x8*)(qrow + lane * 8);
    ushort4 q2 = *(const ushort4*)(qrow + 512 + lane * 4);
#pragma unroll
    for (int i = 0; i < 8; ++i) qv1[i] = bf2f((u16)q1[i]) * 0.125f;
    qv2[0] = bf2f(q2.x) * 0.125f; qv2[1] = bf2f(q2.y) * 0.125f;
    qv2[2] = bf2f(q2.z) * 0.125f; qv2[3] = bf2f(q2.w) * 0.125f;
  }

  float m1 = -__builtin_inff(), l1 = 0.f;
  float m2 = -__builtin_inff(), l2 = 0.f;
  float o1[8] = {}, o2[4] = {};

  auto loadkv = [&](int row, bf16x8& k1, ushort4& k2, bf16x8& v1, ushort4& v2) {
    const u16* kp = QKV + row * QKVN + HH;
    k1 = *(const bf16x8*)(kp + lane * 8);
    k2 = *(const ushort4*)(kp + 512 + lane * 4);
    v1 = *(const bf16x8*)(kp + HH + lane * 8);
    v2 = *(const ushort4*)(kp + HH + 512 + lane * 4);
  };

  if (myn > 0) {
    bf16x8 k1, v1, k1n, v1n;
    ushort4 k2, v2, k2n, v2n;
    loadkv(tailrow[base + half], k1, k2, v1, v2);
    for (int t = 0; t < myn; ++t) {
      int tn = (t + 1 < myn) ? t + 1 : t;   // clamp: harmless reload on last iter
      loadkv(tailrow[base + half + 2 * tn], k1n, k2n, v1n, v2n);

      float s1 = 0.f;
#pragma unroll
      for (int i = 0; i < 8; ++i) s1 += qv1[i] * bf2f((u16)k1[i]);
      s1 += __shfl_xor(s1, 1, 64);
      s1 += __shfl_xor(s1, 2, 64);
      s1 += __shfl_xor(s1, 4, 64);
      float s2 = qv2[0] * bf2f(k2.x) + qv2[1] * bf2f(k2.y) +
                 qv2[2] * bf2f(k2.z) + qv2[3] * bf2f(k2.w);
      s2 += __shfl_xor(s2, 1, 64);
      s2 += __shfl_xor(s2, 2, 64);
      s2 += __shfl_xor(s2, 4, 64);
      s2 += __shfl_xor(s2, 8, 64);

      {
        float mn = fmaxf(m1, s1);
        float al = __expf(m1 - mn);
        float ex = __expf(s1 - mn);
        l1 = l1 * al + ex;
#pragma unroll
        for (int i = 0; i < 8; ++i) o1[i] = o1[i] * al + ex * bf2f((u16)v1[i]);
        m1 = mn;
      }
      {
        float mn = fmaxf(m2, s2);
        float al = __expf(m2 - mn);
        float ex = __expf(s2 - mn);
        l2 = l2 * al + ex;
        o2[0] = o2[0] * al + ex * bf2f(v2.x);
        o2[1] = o2[1] * al + ex * bf2f(v2.y);
        o2[2] = o2[2] * al + ex * bf2f(v2.z);
        o2[3] = o2[3] * al + ex * bf2f(v2.w);
        m2 = mn;
      }
      k1 = k1n; k2 = k2n; v1 = v1n; v2 = v2n;
    }
  }

  // odd wave publishes its state (state-major: lane-contiguous, conflict-free)
  float* sb = sm + sIb * 16 * 64;
  if (half == 1) {
    sb[0 * 64 + lane] = m1;  sb[1 * 64 + lane] = l1;
    sb[2 * 64 + lane] = m2;  sb[3 * 64 + lane] = l2;
#pragma unroll
    for (int i = 0; i < 8; ++i) sb[(4 + i) * 64 + lane] = o1[i];
#pragma unroll
    for (int i = 0; i < 4; ++i) sb[(12 + i) * 64 + lane] = o2[i];
  }
  __syncthreads();
  if (half == 0) {
    float mB1 = sb[0 * 64 + lane], lB1 = sb[1 * 64 + lane];
    float mB2 = sb[2 * 64 + lane], lB2 = sb[3 * 64 + lane];

    float res1[8], res2[4];
    {
      float mn = fmaxf(fmaxf(m1, mB1), -1e30f);
      float aA = __expf(m1 - mn), aB = __expf(mB1 - mn);
      float l = l1 * aA + lB1 * aB;
      float inv = 1.f / fmaxf(l, 1e-9f);
#pragma unroll
      for (int i = 0; i < 8; ++i)
        res1[i] = (o1[i] * aA + sb[(4 + i) * 64 + lane] * aB) * inv;
    }
    {
      float mn = fmaxf(fmaxf(m2, mB2), -1e30f);
      float aA = __expf(m2 - mn), aB = __expf(mB2 - mn);
      float l = l2 * aA + lB2 * aB;
      float inv = 1.f / fmaxf(l, 1e-9f);
#pragma unroll
      for (int i = 0; i < 4; ++i)
        res2[i] = (o2[i] * aA + sb[(12 + i) * 64 + lane] * aB) * inv;
    }

    float* op = out + seg * HH;
    float4 r0 = {res1[0], res1[1], res1[2], res1[3]};
    float4 r1 = {res1[4], res1[5], res1[6], res1[7]};
    float4 r2 = {res2[0], res2[1], res2[2], res2[3]};
    ((float4*)(op + lane * 8))[0] = r0;
    ((float4*)(op + lane * 8))[1] = r1;
    *(float4*)(op + 512 + lane * 4) = r2;
  }
}

// ---------------- launch ----------------
extern "C" void kernel_launch(void* const* d_in, const int* in_sizes, int n_in,
                              void* d_out, int out_size, void* d_ws, size_t ws_size,
                              hipStream_t stream) {
  const float* X  = (const float*)d_in[0];
  const int*   EI = (const int*)d_in[1];
  const float* Wq = (const float*)d_in[2];
  const float* Wk = (const float*)d_in[3];
  const float* Wv = (const float*)d_in[4];
  float* out = (float*)d_out;
  const int E = in_sizes[1] / 4;

  // workspace layout (~56 MB)
  char* ws = (char*)d_ws;
  int* cursor  = (int*)(ws);                 // 32 KB
  int* tailrow = (int*)(ws + 32768);         // NSEG*64*4 = 2 MB
  u16* Xb      = (u16*)(ws + 2129920);       // 8192*768*2  = 12.6 MB
  u16* Wt      = (u16*)(ws + 14712832);      // 2304*768*2  = 3.5 MB
  u16* QKV     = (u16*)(ws + 18251776);      // 8192*2304*2 = 37.7 MB

  hipMemsetAsync(cursor, 0, NSEG * 4, stream);

  cast_x_kernel<<<(NSEG * HH / 4) / 256, 256, 0, stream>>>(X, Xb);
  transpose_w_kernel<<<dim3(QKVN / 32, HH / 32), dim3(32, 8), 0, stream>>>(Wq, Wk, Wv, Wt);
  build_kernel<<<(E + 255) / 256, 256, 0, stream>>>(EI, cursor, tailrow, E);
  gemm_kernel<<<dim3(QKVN / BN, NSEG / BM), 256, 0, stream>>>(Xb, Wt, QKV);
  attn_kernel<<<NSEG / 2, 256, 0, stream>>>(QKV, tailrow, cursor, out);
}

// Round 6
// 177.097 us; speedup vs baseline: 1.9275x; 1.0610x over previous
//
#include <hip/hip_runtime.h>

// Problem constants (fixed by reference)
#define BB 8
#define NN 1024
#define HH 768
#define NHEAD 12
#define HD 64
#define NSEG 8192            // B*N
#define QKVN 2304            // 3*H
#define MAXDEG 64            // bucket capacity per segment (Poisson(16); P(>64) ~ 1e-18)

typedef unsigned short u16;
typedef __attribute__((ext_vector_type(8))) short bf16x8;
typedef __attribute__((ext_vector_type(4))) float f32x4;

__device__ __forceinline__ float bf2f(u16 v) {
  return __uint_as_float(((unsigned)v) << 16);
}
__device__ __forceinline__ u16 f2bf(float f) {
  unsigned u = __float_as_uint(f);
  u += 0x7FFFu + ((u >> 16) & 1u);
  return (u16)(u >> 16);
}

// ---------------- prep: cast node_states fp32 -> bf16 (+ zero cursor) ----------------
__global__ void cast_x_kernel(const float* __restrict__ X, u16* __restrict__ Xb,
                              int* __restrict__ cursor) {
  int i = blockIdx.x * blockDim.x + threadIdx.x;   // one float4 per thread
  if (blockIdx.x < NSEG / 256) cursor[blockIdx.x * 256 + threadIdx.x] = 0;
  float4 f = ((const float4*)X)[i];
  ushort4 o;
  o.x = f2bf(f.x); o.y = f2bf(f.y); o.z = f2bf(f.z); o.w = f2bf(f.w);
  ((ushort4*)Xb)[i] = o;
}

// ------------- prep: build Wt[n][k] = Wsel[k][n] in bf16 -------------
__global__ void transpose_w_kernel(const float* __restrict__ Wq,
                                   const float* __restrict__ Wk,
                                   const float* __restrict__ Wv,
                                   u16* __restrict__ Wt) {
  __shared__ float tile[32][33];
  int n0 = blockIdx.x * 32;
  int k0 = blockIdx.y * 32;
  const float* W = (n0 < HH) ? Wq : (n0 < 2 * HH ? Wk : Wv);
  int nb = n0 - (n0 < HH ? 0 : (n0 < 2 * HH ? HH : 2 * HH));
  int tx = threadIdx.x, ty = threadIdx.y;   // block (32, 8)
#pragma unroll
  for (int r = 0; r < 4; ++r)
    tile[ty + 8 * r][tx] = W[(k0 + ty + 8 * r) * HH + nb + tx];
  __syncthreads();
#pragma unroll
  for (int r = 0; r < 4; ++r)
    Wt[(n0 + ty + 8 * r) * HH + k0 + tx] = f2bf(tile[tx][ty + 8 * r]);
}

// ---------------- CSR build: single bucketed scatter ----------------
__global__ void build_kernel(const int* __restrict__ EI, int* __restrict__ cursor,
                             int* __restrict__ tailrow, int E) {
  int e = blockIdx.x * blockDim.x + threadIdx.x;
  if (e >= E) return;
  int b = EI[e];
  int seg = b * NN + EI[E + e];
  int j = EI[2 * E + e];
  int pos = atomicAdd(&cursor[seg], 1);
  if (pos < MAXDEG) tailrow[seg * MAXDEG + pos] = b * NN + j;
}

// ---------------- fused QKV GEMM: (8192x768) @ (768x2304), bf16 MFMA ----------------
// R6: depth-2 software pipeline. 3 LDS buffers; raw s_barrier with
// s_waitcnt vmcnt(4) (NOT vmcnt(0)) so tile it+1's staging loads stay in
// flight across the barrier — the AITER-style K-loop the __syncthreads
// structure cannot express. Per-wave staging = 4 global_load_lds per tile;
// vmcnt retires in order, so vmcnt(4) == "tile `it` fully landed".
#define BM 128
#define BN 128
#define BK 32
#define NITER (HH / BK)   // 24

__global__ __launch_bounds__(256) void gemm_kernel(const u16* __restrict__ Xb,
                                                   const u16* __restrict__ Wt,
                                                   u16* __restrict__ QKV) {
  __shared__ u16 As[3][BM * BK];   // 3 x 8 KB
  __shared__ u16 Bs[3][BN * BK];   // 3 x 8 KB
  const int tid = threadIdx.x;
  const int wave = tid >> 6;
  const int lane = tid & 63;
  const int m0 = blockIdx.y * BM;
  const int n0 = blockIdx.x * BN;
  const int wr = wave >> 1;
  const int wc = wave & 1;
  const int quad = lane >> 4;
  const int l15 = lane & 15;

  f32x4 acc[4][4] = {};

  const int srow = wave * 16 + (lane >> 2);
  const int scol = (lane & 3) * 8;

  auto stage = [&](int buf, int kt) {
#pragma unroll
    for (int p = 0; p < 2; ++p) {
      const u16* ga = Xb + (m0 + p * 64 + srow) * HH + kt + scol;
      const u16* gb = Wt + (n0 + p * 64 + srow) * HH + kt + scol;
      u16* la = As[buf] + p * 2048 + wave * 512;
      u16* lb = Bs[buf] + p * 2048 + wave * 512;
      __builtin_amdgcn_global_load_lds(
          (const __attribute__((address_space(1))) unsigned int*)(unsigned long long)ga,
          (__attribute__((address_space(3))) unsigned int*)(unsigned long long)la, 16, 0, 0);
      __builtin_amdgcn_global_load_lds(
          (const __attribute__((address_space(1))) unsigned int*)(unsigned long long)gb,
          (__attribute__((address_space(3))) unsigned int*)(unsigned long long)lb, 16, 0, 0);
    }
  };

  stage(0, 0);
  stage(1, BK);

#pragma unroll 3
  for (int it = 0; it < NITER; ++it) {
    // retire exactly tile `it`'s 4 staging loads; keep tile it+1's in flight
    if (it != NITER - 1) {
      asm volatile("s_waitcnt vmcnt(4)" ::: "memory");
    } else {
      asm volatile("s_waitcnt vmcnt(0)" ::: "memory");
    }
    asm volatile("s_barrier" ::: "memory");
    // buf (it+2)%3 was last read at iter it-1 (all waves' ds_reads complete
    // before their barrier at iter `it`) -> safe to overwrite now.
    if (it + 2 < NITER) stage((it + 2) % 3, (it + 2) * BK);

    const int b = it % 3;
    bf16x8 afr[4], bfr[4];
#pragma unroll
    for (int mi = 0; mi < 4; ++mi)
      afr[mi] = *(const bf16x8*)(As[b] + (wr * 64 + mi * 16 + l15) * BK + quad * 8);
#pragma unroll
    for (int ni = 0; ni < 4; ++ni)
      bfr[ni] = *(const bf16x8*)(Bs[b] + (wc * 64 + ni * 16 + l15) * BK + quad * 8);
#pragma unroll
    for (int mi = 0; mi < 4; ++mi)
#pragma unroll
      for (int ni = 0; ni < 4; ++ni)
        acc[mi][ni] = __builtin_amdgcn_mfma_f32_16x16x32_bf16(afr[mi], bfr[ni], acc[mi][ni], 0, 0, 0);
  }

  // epilogue: C/D layout col=lane&15, row=(lane>>4)*4+reg  [m89-verified]
#pragma unroll
  for (int mi = 0; mi < 4; ++mi)
#pragma unroll
    for (int ni = 0; ni < 4; ++ni) {
      int col = n0 + wc * 64 + ni * 16 + l15;
#pragma unroll
      for (int r = 0; r < 4; ++r) {
        int row = m0 + wr * 64 + mi * 16 + quad * 4 + r;
        QKV[row * QKVN + col] = f2bf(acc[mi][ni][r]);
      }
    }
}

// ---------------- attention: TWO waves per segment, LDS merge, XCD swizzle ----------------
// Lane mapping (R2-verified): lane owns dims [8L,8L+8) (heads 0..7, 8-lane
// reduce) + dims [512+4L,512+4L+4) (heads 8..11, 16-lane reduce).
// R6: XCD-affinity swizzle — dispatch assigns block -> XCD round-robin
// (blockIdx%8), so map batch b's 512 blocks to residue class b. Per-XCD K/V
// working set = one batch = 3 MB < 4 MB L2 (was 24 MB across all batches).
__global__ __launch_bounds__(256) void attn_kernel(const u16* __restrict__ QKV,
                                                   const int* __restrict__ tailrow,
                                                   const int* __restrict__ cursor,
                                                   float* __restrict__ out) {
  __shared__ float sm[2 * 16 * 64];   // [seg-in-block][16 states][64 lanes] = 8 KB
  const int wv = threadIdx.x >> 6;    // 0..3
  const int lane = threadIdx.x & 63;
  const int sIb = wv >> 1;            // segment within block
  const int half = wv & 1;            // which half of the edge list
  const int blk = (blockIdx.x & 7) * (NSEG / 16) + (blockIdx.x >> 3);  // batch = blk/512
  const int seg = blk * 2 + sIb;
  const int base = seg * MAXDEG;
  int cnt = cursor[seg];
  if (cnt > MAXDEG) cnt = MAXDEG;
  const int myn = (cnt > half) ? ((cnt - half + 1) >> 1) : 0;   // edges at half, half+2, ...

  // preload q (scaled by 1/sqrt(64))
  const u16* qrow = QKV + seg * QKVN;
  float qv1[8], qv2[4];
  {
    bf16x8 q1 = *(const bf16x8*)(qrow + lane * 8);
    ushort4 q2 = *(const ushort4*)(qrow + 512 + lane * 4);
#pragma unroll
    for (int i = 0; i < 8; ++i) qv1[i] = bf2f((u16)q1[i]) * 0.125f;
    qv2[0] = bf2f(q2.x) * 0.125f; qv2[1] = bf2f(q2.y) * 0.125f;
    qv2[2] = bf2f(q2.z) * 0.125f; qv2[3] = bf2f(q2.w) * 0.125f;
  }

  float m1 = -__builtin_inff(), l1 = 0.f;
  float m2 = -__builtin_inff(), l2 = 0.f;
  float o1[8] = {}, o2[4] = {};

  auto loadkv = [&](int row, bf16x8& k1, ushort4& k2, bf16x8& v1, ushort4& v2) {
    const u16* kp = QKV + row * QKVN + HH;
    k1 = *(const bf16x8*)(kp + lane * 8);
    k2 = *(const ushort4*)(kp + 512 + lane * 4);
    v1 = *(const bf16x8*)(kp + HH + lane * 8);
    v2 = *(const ushort4*)(kp + HH + 512 + lane * 4);
  };

  if (myn > 0) {
    bf16x8 k1, v1, k1n, v1n;
    ushort4 k2, v2, k2n, v2n;
    loadkv(tailrow[base + half], k1, k2, v1, v2);
    for (int t = 0; t < myn; ++t) {
      int tn = (t + 1 < myn) ? t + 1 : t;   // clamp: harmless reload on last iter
      loadkv(tailrow[base + half + 2 * tn], k1n, k2n, v1n, v2n);

      float s1 = 0.f;
#pragma unroll
      for (int i = 0; i < 8; ++i) s1 += qv1[i] * bf2f((u16)k1[i]);
      s1 += __shfl_xor(s1, 1, 64);
      s1 += __shfl_xor(s1, 2, 64);
      s1 += __shfl_xor(s1, 4, 64);
      float s2 = qv2[0] * bf2f(k2.x) + qv2[1] * bf2f(k2.y) +
                 qv2[2] * bf2f(k2.z) + qv2[3] * bf2f(k2.w);
      s2 += __shfl_xor(s2, 1, 64);
      s2 += __shfl_xor(s2, 2, 64);
      s2 += __shfl_xor(s2, 4, 64);
      s2 += __shfl_xor(s2, 8, 64);

      {
        float mn = fmaxf(m1, s1);
        float al = __expf(m1 - mn);
        float ex = __expf(s1 - mn);
        l1 = l1 * al + ex;
#pragma unroll
        for (int i = 0; i < 8; ++i) o1[i] = o1[i] * al + ex * bf2f((u16)v1[i]);
        m1 = mn;
      }
      {
        float mn = fmaxf(m2, s2);
        float al = __expf(m2 - mn);
        float ex = __expf(s2 - mn);
        l2 = l2 * al + ex;
        o2[0] = o2[0] * al + ex * bf2f(v2.x);
        o2[1] = o2[1] * al + ex * bf2f(v2.y);
        o2[2] = o2[2] * al + ex * bf2f(v2.z);
        o2[3] = o2[3] * al + ex * bf2f(v2.w);
        m2 = mn;
      }
      k1 = k1n; k2 = k2n; v1 = v1n; v2 = v2n;
    }
  }

  // odd wave publishes its state (state-major: lane-contiguous, conflict-free)
  float* sb = sm + sIb * 16 * 64;
  if (half == 1) {
    sb[0 * 64 + lane] = m1;  sb[1 * 64 + lane] = l1;
    sb[2 * 64 + lane] = m2;  sb[3 * 64 + lane] = l2;
#pragma unroll
    for (int i = 0; i < 8; ++i) sb[(4 + i) * 64 + lane] = o1[i];
#pragma unroll
    for (int i = 0; i < 4; ++i) sb[(12 + i) * 64 + lane] = o2[i];
  }
  __syncthreads();
  if (half == 0) {
    float mB1 = sb[0 * 64 + lane], lB1 = sb[1 * 64 + lane];
    float mB2 = sb[2 * 64 + lane], lB2 = sb[3 * 64 + lane];

    float res1[8], res2[4];
    {
      float mn = fmaxf(fmaxf(m1, mB1), -1e30f);
      float aA = __expf(m1 - mn), aB = __expf(mB1 - mn);
      float l = l1 * aA + lB1 * aB;
      float inv = 1.f / fmaxf(l, 1e-9f);
#pragma unroll
      for (int i = 0; i < 8; ++i)
        res1[i] = (o1[i] * aA + sb[(4 + i) * 64 + lane] * aB) * inv;
    }
    {
      float mn = fmaxf(fmaxf(m2, mB2), -1e30f);
      float aA = __expf(m2 - mn), aB = __expf(mB2 - mn);
      float l = l2 * aA + lB2 * aB;
      float inv = 1.f / fmaxf(l, 1e-9f);
#pragma unroll
      for (int i = 0; i < 4; ++i)
        res2[i] = (o2[i] * aA + sb[(12 + i) * 64 + lane] * aB) * inv;
    }

    float* op = out + seg * HH;
    float4 r0 = {res1[0], res1[1], res1[2], res1[3]};
    float4 r1 = {res1[4], res1[5], res1[6], res1[7]};
    float4 r2 = {res2[0], res2[1], res2[2], res2[3]};
    ((float4*)(op + lane * 8))[0] = r0;
    ((float4*)(op + lane * 8))[1] = r1;
    *(float4*)(op + 512 + lane * 4) = r2;
  }
}

// ---------------- launch ----------------
extern "C" void kernel_launch(void* const* d_in, const int* in_sizes, int n_in,
                              void* d_out, int out_size, void* d_ws, size_t ws_size,
                              hipStream_t stream) {
  const float* X  = (const float*)d_in[0];
  const int*   EI = (const int*)d_in[1];
  const float* Wq = (const float*)d_in[2];
  const float* Wk = (const float*)d_in[3];
  const float* Wv = (const float*)d_in[4];
  float* out = (float*)d_out;
  const int E = in_sizes[1] / 4;

  // workspace layout (~56 MB)
  char* ws = (char*)d_ws;
  int* cursor  = (int*)(ws);                 // 32 KB
  int* tailrow = (int*)(ws + 32768);         // NSEG*64*4 = 2 MB
  u16* Xb      = (u16*)(ws + 2129920);       // 8192*768*2  = 12.6 MB
  u16* Wt      = (u16*)(ws + 14712832);      // 2304*768*2  = 3.5 MB
  u16* QKV     = (u16*)(ws + 18251776);      // 8192*2304*2 = 37.7 MB

  cast_x_kernel<<<(NSEG * HH / 4) / 256, 256, 0, stream>>>(X, Xb, cursor);
  transpose_w_kernel<<<dim3(QKVN / 32, HH / 32), dim3(32, 8), 0, stream>>>(Wq, Wk, Wv, Wt);
  build_kernel<<<(E + 255) / 256, 256, 0, stream>>>(EI, cursor, tailrow, E);
  gemm_kernel<<<dim3(QKVN / BN, NSEG / BM), 256, 0, stream>>>(Xb, Wt, QKV);
  attn_kernel<<<NSEG / 2, 256, 0, stream>>>(QKV, tailrow, cursor, out);
}

// Round 7
// 177.038 us; speedup vs baseline: 1.9281x; 1.0003x over previous
//
#include <hip/hip_runtime.h>

// Problem constants (fixed by reference)
#define BB 8
#define NN 1024
#define HH 768
#define NHEAD 12
#define HD 64
#define NSEG 8192            // B*N
#define QKVN 2304            // 3*H
#define MAXDEG 64            // bucket capacity per segment (Poisson(16); P(>64) ~ 1e-18)

typedef unsigned short u16;
typedef __attribute__((ext_vector_type(8))) short bf16x8;
typedef __attribute__((ext_vector_type(4))) float f32x4;

__device__ __forceinline__ float bf2f(u16 v) {
  return __uint_as_float(((unsigned)v) << 16);
}
__device__ __forceinline__ u16 f2bf(float f) {
  unsigned u = __float_as_uint(f);
  u += 0x7FFFu + ((u >> 16) & 1u);
  return (u16)(u >> 16);
}

// ---------------- fused prep: cast X, transpose W, build CSR ----------------
// The three jobs are mutually independent (disjoint reads/writes); cursor is
// zeroed by a preceding hipMemsetAsync. Block roles by blockIdx range:
//   [0, 6144)        cast:      one float4 per thread of X -> Xb (bf16)
//   [6144, 7872)     transpose: 1728 32x32 tiles of [Wq|Wk|Wv] -> Wt (2304x768 bf16)
//   [7872, 8384)     build:     bucketed scatter of edges -> tailrow
#define CAST_BLKS (NSEG * HH / 4 / 256)     // 6144
#define TW_BLKS   ((QKVN / 32) * (HH / 32)) // 1728
#define BUILD_BLKS 512

__global__ void prep_kernel(const float* __restrict__ X, u16* __restrict__ Xb,
                            const float* __restrict__ Wq, const float* __restrict__ Wk,
                            const float* __restrict__ Wv, u16* __restrict__ Wt,
                            const int* __restrict__ EI, int* __restrict__ cursor,
                            int* __restrict__ tailrow, int E) {
  const int bid = blockIdx.x;
  if (bid < CAST_BLKS) {
    int i = bid * 256 + threadIdx.x;
    float4 f = ((const float4*)X)[i];
    ushort4 o;
    o.x = f2bf(f.x); o.y = f2bf(f.y); o.z = f2bf(f.z); o.w = f2bf(f.w);
    ((ushort4*)Xb)[i] = o;
  } else if (bid < CAST_BLKS + TW_BLKS) {
    __shared__ float tile[32][33];
    int t = bid - CAST_BLKS;
    int n0 = (t % (QKVN / 32)) * 32;
    int k0 = (t / (QKVN / 32)) * 32;
    const float* W = (n0 < HH) ? Wq : (n0 < 2 * HH ? Wk : Wv);
    int nb = n0 - (n0 < HH ? 0 : (n0 < 2 * HH ? HH : 2 * HH));
    int tx = threadIdx.x & 31, ty = threadIdx.x >> 5;   // (32, 8)
#pragma unroll
    for (int r = 0; r < 4; ++r)
      tile[ty + 8 * r][tx] = W[(k0 + ty + 8 * r) * HH + nb + tx];
    __syncthreads();
#pragma unroll
    for (int r = 0; r < 4; ++r)
      Wt[(n0 + ty + 8 * r) * HH + k0 + tx] = f2bf(tile[tx][ty + 8 * r]);
  } else {
    int e = (bid - CAST_BLKS - TW_BLKS) * 256 + threadIdx.x;
    if (e >= E) return;
    int b = EI[e];
    int seg = b * NN + EI[E + e];
    int j = EI[2 * E + e];
    int pos = atomicAdd(&cursor[seg], 1);
    if (pos < MAXDEG) tailrow[seg * MAXDEG + pos] = b * NN + j;
  }
}

// ---------------- fused QKV GEMM: (8192x768) @ (768x2304), bf16 MFMA ----------------
// R6-verified: depth-2 software pipeline. 3 LDS buffers; raw s_barrier with
// s_waitcnt vmcnt(4) so tile it+1's staging loads stay in flight across the
// barrier. Per-wave staging = 4 global_load_lds per tile; vmcnt retires in
// order, so vmcnt(4) == "tile `it` fully landed".
#define BM 128
#define BN 128
#define BK 32
#define NITER (HH / BK)   // 24

__global__ __launch_bounds__(256) void gemm_kernel(const u16* __restrict__ Xb,
                                                   const u16* __restrict__ Wt,
                                                   u16* __restrict__ QKV) {
  __shared__ u16 As[3][BM * BK];   // 3 x 8 KB
  __shared__ u16 Bs[3][BN * BK];   // 3 x 8 KB
  const int tid = threadIdx.x;
  const int wave = tid >> 6;
  const int lane = tid & 63;
  const int m0 = blockIdx.y * BM;
  const int n0 = blockIdx.x * BN;
  const int wr = wave >> 1;
  const int wc = wave & 1;
  const int quad = lane >> 4;
  const int l15 = lane & 15;

  f32x4 acc[4][4] = {};

  const int srow = wave * 16 + (lane >> 2);
  const int scol = (lane & 3) * 8;

  auto stage = [&](int buf, int kt) {
#pragma unroll
    for (int p = 0; p < 2; ++p) {
      const u16* ga = Xb + (m0 + p * 64 + srow) * HH + kt + scol;
      const u16* gb = Wt + (n0 + p * 64 + srow) * HH + kt + scol;
      u16* la = As[buf] + p * 2048 + wave * 512;
      u16* lb = Bs[buf] + p * 2048 + wave * 512;
      __builtin_amdgcn_global_load_lds(
          (const __attribute__((address_space(1))) unsigned int*)(unsigned long long)ga,
          (__attribute__((address_space(3))) unsigned int*)(unsigned long long)la, 16, 0, 0);
      __builtin_amdgcn_global_load_lds(
          (const __attribute__((address_space(1))) unsigned int*)(unsigned long long)gb,
          (__attribute__((address_space(3))) unsigned int*)(unsigned long long)lb, 16, 0, 0);
    }
  };

  stage(0, 0);
  stage(1, BK);

#pragma unroll 3
  for (int it = 0; it < NITER; ++it) {
    if (it != NITER - 1) {
      asm volatile("s_waitcnt vmcnt(4)" ::: "memory");
    } else {
      asm volatile("s_waitcnt vmcnt(0)" ::: "memory");
    }
    asm volatile("s_barrier" ::: "memory");
    if (it + 2 < NITER) stage((it + 2) % 3, (it + 2) * BK);

    const int b = it % 3;
    bf16x8 afr[4], bfr[4];
#pragma unroll
    for (int mi = 0; mi < 4; ++mi)
      afr[mi] = *(const bf16x8*)(As[b] + (wr * 64 + mi * 16 + l15) * BK + quad * 8);
#pragma unroll
    for (int ni = 0; ni < 4; ++ni)
      bfr[ni] = *(const bf16x8*)(Bs[b] + (wc * 64 + ni * 16 + l15) * BK + quad * 8);
#pragma unroll
    for (int mi = 0; mi < 4; ++mi)
#pragma unroll
      for (int ni = 0; ni < 4; ++ni)
        acc[mi][ni] = __builtin_amdgcn_mfma_f32_16x16x32_bf16(afr[mi], bfr[ni], acc[mi][ni], 0, 0, 0);
  }

  // epilogue: C/D layout col=lane&15, row=(lane>>4)*4+reg  [m89-verified]
#pragma unroll
  for (int mi = 0; mi < 4; ++mi)
#pragma unroll
    for (int ni = 0; ni < 4; ++ni) {
      int col = n0 + wc * 64 + ni * 16 + l15;
#pragma unroll
      for (int r = 0; r < 4; ++r) {
        int row = m0 + wr * 64 + mi * 16 + quad * 4 + r;
        QKV[row * QKVN + col] = f2bf(acc[mi][ni][r]);
      }
    }
}

// ---------------- attention: TWO waves per segment, LDS merge, XCD swizzle ----------------
// (unchanged from R6)
__global__ __launch_bounds__(256) void attn_kernel(const u16* __restrict__ QKV,
                                                   const int* __restrict__ tailrow,
                                                   const int* __restrict__ cursor,
                                                   float* __restrict__ out) {
  __shared__ float sm[2 * 16 * 64];   // [seg-in-block][16 states][64 lanes] = 8 KB
  const int wv = threadIdx.x >> 6;    // 0..3
  const int lane = threadIdx.x & 63;
  const int sIb = wv >> 1;            // segment within block
  const int half = wv & 1;            // which half of the edge list
  const int blk = (blockIdx.x & 7) * (NSEG / 16) + (blockIdx.x >> 3);  // batch = blk/512
  const int seg = blk * 2 + sIb;
  const int base = seg * MAXDEG;
  int cnt = cursor[seg];
  if (cnt > MAXDEG) cnt = MAXDEG;
  const int myn = (cnt > half) ? ((cnt - half + 1) >> 1) : 0;   // edges at half, half+2, ...

  // preload q (scaled by 1/sqrt(64))
  const u16* qrow = QKV + seg * QKVN;
  float qv1[8], qv2[4];
  {
    bf16x8 q1 = *(const bf16x8*)(qrow + lane * 8);
    ushort4 q2 = *(const ushort4*)(qrow + 512 + lane * 4);
#pragma unroll
    for (int i = 0; i < 8; ++i) qv1[i] = bf2f((u16)q1[i]) * 0.125f;
    qv2[0] = bf2f(q2.x) * 0.125f; qv2[1] = bf2f(q2.y) * 0.125f;
    qv2[2] = bf2f(q2.z) * 0.125f; qv2[3] = bf2f(q2.w) * 0.125f;
  }

  float m1 = -__builtin_inff(), l1 = 0.f;
  float m2 = -__builtin_inff(), l2 = 0.f;
  float o1[8] = {}, o2[4] = {};

  auto loadkv = [&](int row, bf16x8& k1, ushort4& k2, bf16x8& v1, ushort4& v2) {
    const u16* kp = QKV + row * QKVN + HH;
    k1 = *(const bf16x8*)(kp + lane * 8);
    k2 = *(const ushort4*)(kp + 512 + lane * 4);
    v1 = *(const bf16x8*)(kp + HH + lane * 8);
    v2 = *(const ushort4*)(kp + HH + 512 + lane * 4);
  };

  if (myn > 0) {
    bf16x8 k1, v1, k1n, v1n;
    ushort4 k2, v2, k2n, v2n;
    loadkv(tailrow[base + half], k1, k2, v1, v2);
    for (int t = 0; t < myn; ++t) {
      int tn = (t + 1 < myn) ? t + 1 : t;   // clamp: harmless reload on last iter
      loadkv(tailrow[base + half + 2 * tn], k1n, k2n, v1n, v2n);

      float s1 = 0.f;
#pragma unroll
      for (int i = 0; i < 8; ++i) s1 += qv1[i] * bf2f((u16)k1[i]);
      s1 += __shfl_xor(s1, 1, 64);
      s1 += __shfl_xor(s1, 2, 64);
      s1 += __shfl_xor(s1, 4, 64);
      float s2 = qv2[0] * bf2f(k2.x) + qv2[1] * bf2f(k2.y) +
                 qv2[2] * bf2f(k2.z) + qv2[3] * bf2f(k2.w);
      s2 += __shfl_xor(s2, 1, 64);
      s2 += __shfl_xor(s2, 2, 64);
      s2 += __shfl_xor(s2, 4, 64);
      s2 += __shfl_xor(s2, 8, 64);

      {
        float mn = fmaxf(m1, s1);
        float al = __expf(m1 - mn);
        float ex = __expf(s1 - mn);
        l1 = l1 * al + ex;
#pragma unroll
        for (int i = 0; i < 8; ++i) o1[i] = o1[i] * al + ex * bf2f((u16)v1[i]);
        m1 = mn;
      }
      {
        float mn = fmaxf(m2, s2);
        float al = __expf(m2 - mn);
        float ex = __expf(s2 - mn);
        l2 = l2 * al + ex;
        o2[0] = o2[0] * al + ex * bf2f(v2.x);
        o2[1] = o2[1] * al + ex * bf2f(v2.y);
        o2[2] = o2[2] * al + ex * bf2f(v2.z);
        o2[3] = o2[3] * al + ex * bf2f(v2.w);
        m2 = mn;
      }
      k1 = k1n; k2 = k2n; v1 = v1n; v2 = v2n;
    }
  }

  // odd wave publishes its state (state-major: lane-contiguous, conflict-free)
  float* sb = sm + sIb * 16 * 64;
  if (half == 1) {
    sb[0 * 64 + lane] = m1;  sb[1 * 64 + lane] = l1;
    sb[2 * 64 + lane] = m2;  sb[3 * 64 + lane] = l2;
#pragma unroll
    for (int i = 0; i < 8; ++i) sb[(4 + i) * 64 + lane] = o1[i];
#pragma unroll
    for (int i = 0; i < 4; ++i) sb[(12 + i) * 64 + lane] = o2[i];
  }
  __syncthreads();
  if (half == 0) {
    float mB1 = sb[0 * 64 + lane], lB1 = sb[1 * 64 + lane];
    float mB2 = sb[2 * 64 + lane], lB2 = sb[3 * 64 + lane];

    float res1[8], res2[4];
    {
      float mn = fmaxf(fmaxf(m1, mB1), -1e30f);
      float aA = __expf(m1 - mn), aB = __expf(mB1 - mn);
      float l = l1 * aA + lB1 * aB;
      float inv = 1.f / fmaxf(l, 1e-9f);
#pragma unroll
      for (int i = 0; i < 8; ++i)
        res1[i] = (o1[i] * aA + sb[(4 + i) * 64 + lane] * aB) * inv;
    }
    {
      float mn = fmaxf(fmaxf(m2, mB2), -1e30f);
      float aA = __expf(m2 - mn), aB = __expf(mB2 - mn);
      float l = l2 * aA + lB2 * aB;
      float inv = 1.f / fmaxf(l, 1e-9f);
#pragma unroll
      for (int i = 0; i < 4; ++i)
        res2[i] = (o2[i] * aA + sb[(12 + i) * 64 + lane] * aB) * inv;
    }

    float* op = out + seg * HH;
    float4 r0 = {res1[0], res1[1], res1[2], res1[3]};
    float4 r1 = {res1[4], res1[5], res1[6], res1[7]};
    float4 r2 = {res2[0], res2[1], res2[2], res2[3]};
    ((float4*)(op + lane * 8))[0] = r0;
    ((float4*)(op + lane * 8))[1] = r1;
    *(float4*)(op + 512 + lane * 4) = r2;
  }
}

// ---------------- launch ----------------
extern "C" void kernel_launch(void* const* d_in, const int* in_sizes, int n_in,
                              void* d_out, int out_size, void* d_ws, size_t ws_size,
                              hipStream_t stream) {
  const float* X  = (const float*)d_in[0];
  const int*   EI = (const int*)d_in[1];
  const float* Wq = (const float*)d_in[2];
  const float* Wk = (const float*)d_in[3];
  const float* Wv = (const float*)d_in[4];
  float* out = (float*)d_out;
  const int E = in_sizes[1] / 4;

  // workspace layout (~56 MB)
  char* ws = (char*)d_ws;
  int* cursor  = (int*)(ws);                 // 32 KB
  int* tailrow = (int*)(ws + 32768);         // NSEG*64*4 = 2 MB
  u16* Xb      = (u16*)(ws + 2129920);       // 8192*768*2  = 12.6 MB
  u16* Wt      = (u16*)(ws + 14712832);      // 2304*768*2  = 3.5 MB
  u16* QKV     = (u16*)(ws + 18251776);      // 8192*2304*2 = 37.7 MB

  hipMemsetAsync(cursor, 0, NSEG * 4, stream);   // cheap dispatch, orders before prep
  prep_kernel<<<CAST_BLKS + TW_BLKS + BUILD_BLKS, 256, 0, stream>>>(
      X, Xb, Wq, Wk, Wv, Wt, EI, cursor, tailrow, E);
  gemm_kernel<<<dim3(QKVN / BN, NSEG / BM), 256, 0, stream>>>(Xb, Wt, QKV);
  attn_kernel<<<NSEG / 2, 256, 0, stream>>>(QKV, tailrow, cursor, out);
}

// Round 8
// 169.637 us; speedup vs baseline: 2.0122x; 1.0436x over previous
//
#include <hip/hip_runtime.h>
#include <hip/hip_fp16.h>

// Problem constants (fixed by reference)
#define BB 8
#define NN 1024
#define HH 768
#define NHEAD 12
#define HD 64
#define NSEG 8192            // B*N
#define QKVN 2304            // 3*H
#define MAXDEG 64            // bucket capacity per segment (Poisson(16); P(>64) ~ 1e-18)

typedef unsigned short u16;
typedef __attribute__((ext_vector_type(8))) _Float16 f16x8;
typedef __attribute__((ext_vector_type(4))) float f32x4;
typedef __attribute__((ext_vector_type(4))) unsigned int u32x4;
typedef __attribute__((ext_vector_type(2))) unsigned int u32x2;

__device__ __forceinline__ u16 f2h(float f) {
  _Float16 h = (_Float16)f;
  return __builtin_bit_cast(u16, h);
}
__device__ __forceinline__ __half2 h2(unsigned int w) {
  return __builtin_bit_cast(__half2, w);
}

// ---------------- fused prep: cast X, transpose W, build CSR ----------------
// All intermediates (Xb, Wt, QKV) are f16: enables packed v_pk_fma_f16 in attn
// and improves precision vs bf16 (values bounded ~|20|, well inside f16 range).
#define CAST_BLKS (NSEG * HH / 4 / 256)     // 6144
#define TW_BLKS   ((QKVN / 32) * (HH / 32)) // 1728
#define BUILD_BLKS 512

__global__ void prep_kernel(const float* __restrict__ X, u16* __restrict__ Xb,
                            const float* __restrict__ Wq, const float* __restrict__ Wk,
                            const float* __restrict__ Wv, u16* __restrict__ Wt,
                            const int* __restrict__ EI, int* __restrict__ cursor,
                            int* __restrict__ tailrow, int E) {
  const int bid = blockIdx.x;
  if (bid < CAST_BLKS) {
    int i = bid * 256 + threadIdx.x;
    float4 f = ((const float4*)X)[i];
    ushort4 o;
    o.x = f2h(f.x); o.y = f2h(f.y); o.z = f2h(f.z); o.w = f2h(f.w);
    ((ushort4*)Xb)[i] = o;
  } else if (bid < CAST_BLKS + TW_BLKS) {
    __shared__ float tile[32][33];
    int t = bid - CAST_BLKS;
    int n0 = (t % (QKVN / 32)) * 32;
    int k0 = (t / (QKVN / 32)) * 32;
    const float* W = (n0 < HH) ? Wq : (n0 < 2 * HH ? Wk : Wv);
    int nb = n0 - (n0 < HH ? 0 : (n0 < 2 * HH ? HH : 2 * HH));
    int tx = threadIdx.x & 31, ty = threadIdx.x >> 5;   // (32, 8)
#pragma unroll
    for (int r = 0; r < 4; ++r)
      tile[ty + 8 * r][tx] = W[(k0 + ty + 8 * r) * HH + nb + tx];
    __syncthreads();
#pragma unroll
    for (int r = 0; r < 4; ++r)
      Wt[(n0 + ty + 8 * r) * HH + k0 + tx] = f2h(tile[tx][ty + 8 * r]);
  } else {
    int e = (bid - CAST_BLKS - TW_BLKS) * 256 + threadIdx.x;
    if (e >= E) return;
    int b = EI[e];
    int seg = b * NN + EI[E + e];
    int j = EI[2 * E + e];
    int pos = atomicAdd(&cursor[seg], 1);
    if (pos < MAXDEG) tailrow[seg * MAXDEG + pos] = b * NN + j;
  }
}

// ---------------- fused QKV GEMM: (8192x768) @ (768x2304), f16 MFMA ----------------
// R6-verified depth-2 pipeline: 3 LDS buffers, raw s_barrier with
// s_waitcnt vmcnt(4) so next tile's staging stays in flight across the barrier.
#define BM 128
#define BN 128
#define BK 32
#define NITER (HH / BK)   // 24

__global__ __launch_bounds__(256) void gemm_kernel(const u16* __restrict__ Xb,
                                                   const u16* __restrict__ Wt,
                                                   u16* __restrict__ QKV) {
  __shared__ u16 As[3][BM * BK];   // 3 x 8 KB
  __shared__ u16 Bs[3][BN * BK];   // 3 x 8 KB
  const int tid = threadIdx.x;
  const int wave = tid >> 6;
  const int lane = tid & 63;
  const int m0 = blockIdx.y * BM;
  const int n0 = blockIdx.x * BN;
  const int wr = wave >> 1;
  const int wc = wave & 1;
  const int quad = lane >> 4;
  const int l15 = lane & 15;

  f32x4 acc[4][4] = {};

  const int srow = wave * 16 + (lane >> 2);
  const int scol = (lane & 3) * 8;

  auto stage = [&](int buf, int kt) {
#pragma unroll
    for (int p = 0; p < 2; ++p) {
      const u16* ga = Xb + (m0 + p * 64 + srow) * HH + kt + scol;
      const u16* gb = Wt + (n0 + p * 64 + srow) * HH + kt + scol;
      u16* la = As[buf] + p * 2048 + wave * 512;
      u16* lb = Bs[buf] + p * 2048 + wave * 512;
      __builtin_amdgcn_global_load_lds(
          (const __attribute__((address_space(1))) unsigned int*)(unsigned long long)ga,
          (__attribute__((address_space(3))) unsigned int*)(unsigned long long)la, 16, 0, 0);
      __builtin_amdgcn_global_load_lds(
          (const __attribute__((address_space(1))) unsigned int*)(unsigned long long)gb,
          (__attribute__((address_space(3))) unsigned int*)(unsigned long long)lb, 16, 0, 0);
    }
  };

  stage(0, 0);
  stage(1, BK);

#pragma unroll 3
  for (int it = 0; it < NITER; ++it) {
    if (it != NITER - 1) {
      asm volatile("s_waitcnt vmcnt(4)" ::: "memory");
    } else {
      asm volatile("s_waitcnt vmcnt(0)" ::: "memory");
    }
    asm volatile("s_barrier" ::: "memory");
    if (it + 2 < NITER) stage((it + 2) % 3, (it + 2) * BK);

    const int b = it % 3;
    f16x8 afr[4], bfr[4];
#pragma unroll
    for (int mi = 0; mi < 4; ++mi)
      afr[mi] = *(const f16x8*)(As[b] + (wr * 64 + mi * 16 + l15) * BK + quad * 8);
#pragma unroll
    for (int ni = 0; ni < 4; ++ni)
      bfr[ni] = *(const f16x8*)(Bs[b] + (wc * 64 + ni * 16 + l15) * BK + quad * 8);
#pragma unroll
    for (int mi = 0; mi < 4; ++mi)
#pragma unroll
      for (int ni = 0; ni < 4; ++ni)
        acc[mi][ni] = __builtin_amdgcn_mfma_f32_16x16x32_f16(afr[mi], bfr[ni], acc[mi][ni], 0, 0, 0);
  }

  // epilogue: C/D layout col=lane&15, row=(lane>>4)*4+reg  [m89-verified]
#pragma unroll
  for (int mi = 0; mi < 4; ++mi)
#pragma unroll
    for (int ni = 0; ni < 4; ++ni) {
      int col = n0 + wc * 64 + ni * 16 + l15;
#pragma unroll
      for (int r = 0; r < 4; ++r) {
        int row = m0 + wr * 64 + mi * 16 + quad * 4 + r;
        QKV[row * QKVN + col] = f2h(acc[mi][ni][r]);
      }
    }
}

// ---------------- attention: 2 waves/segment, packed-f16 math, XCD swizzle ----------------
// Lane mapping (R2-verified): lane owns dims [8L,8L+8) (heads 0..7, 8-lane
// reduce) + dims [512+4L,512+4L+4) (heads 8..11, 16-lane reduce).
// R8: QKV is f16 -> score and o-update use v_pk_fma_f16 (__hfma2), cutting
// per-edge VALU ~85 -> ~40. o accumulates in f16 pairs (err ~2e-3 << thresh).
__global__ __launch_bounds__(256) void attn_kernel(const u16* __restrict__ QKV,
                                                   const int* __restrict__ tailrow,
                                                   const int* __restrict__ cursor,
                                                   float* __restrict__ out) {
  __shared__ float sm[2 * 16 * 64];   // [seg-in-block][16 states][64 lanes] = 8 KB
  const int wv = threadIdx.x >> 6;    // 0..3
  const int lane = threadIdx.x & 63;
  const int sIb = wv >> 1;            // segment within block
  const int half = wv & 1;            // which half of the edge list
  const int blk = (blockIdx.x & 7) * (NSEG / 16) + (blockIdx.x >> 3);  // XCD affinity: batch = blk/512
  const int seg = blk * 2 + sIb;
  const int base = seg * MAXDEG;
  int cnt = cursor[seg];
  if (cnt > MAXDEG) cnt = MAXDEG;
  const int myn = (cnt > half) ? ((cnt - half + 1) >> 1) : 0;   // edges at half, half+2, ...

  // preload q (scaled by 1/sqrt(64)=0.125, exact in f16)
  const u16* qrow = QKV + seg * QKVN;
  __half2 q1[4], q2[2];
  {
    u32x4 qa = *(const u32x4*)(qrow + lane * 8);
    u32x2 qb = *(const u32x2*)(qrow + 512 + lane * 4);
    const __half2 sc = __float2half2_rn(0.125f);
#pragma unroll
    for (int i = 0; i < 4; ++i) q1[i] = __hmul2(h2(qa[i]), sc);
    q2[0] = __hmul2(h2(qb[0]), sc);
    q2[1] = __hmul2(h2(qb[1]), sc);
  }

  float m1 = -__builtin_inff(), l1 = 0.f;
  float m2 = -__builtin_inff(), l2 = 0.f;
  __half2 o1[4] = {}, o2[2] = {};   // zero-init packed accumulators

  auto loadkv = [&](int row, u32x4& k1, u32x2& k2, u32x4& v1, u32x2& v2) {
    const u16* kp = QKV + row * QKVN + HH;
    k1 = *(const u32x4*)(kp + lane * 8);
    k2 = *(const u32x2*)(kp + 512 + lane * 4);
    v1 = *(const u32x4*)(kp + HH + lane * 8);
    v2 = *(const u32x2*)(kp + HH + 512 + lane * 4);
  };

  if (myn > 0) {
    u32x4 k1, v1, k1n, v1n;
    u32x2 k2, v2, k2n, v2n;
    loadkv(tailrow[base + half], k1, k2, v1, v2);
    for (int t = 0; t < myn; ++t) {
      int tn = (t + 1 < myn) ? t + 1 : t;   // clamp: harmless reload on last iter
      loadkv(tailrow[base + half + 2 * tn], k1n, k2n, v1n, v2n);

      // scores via packed f16 fma
      __half2 a1 = __hmul2(q1[0], h2(k1[0]));
      a1 = __hfma2(q1[1], h2(k1[1]), a1);
      a1 = __hfma2(q1[2], h2(k1[2]), a1);
      a1 = __hfma2(q1[3], h2(k1[3]), a1);
      float s1 = __low2float(a1) + __high2float(a1);
      s1 += __shfl_xor(s1, 1, 64);
      s1 += __shfl_xor(s1, 2, 64);
      s1 += __shfl_xor(s1, 4, 64);
      __half2 a2 = __hmul2(q2[0], h2(k2[0]));
      a2 = __hfma2(q2[1], h2(k2[1]), a2);
      float s2 = __low2float(a2) + __high2float(a2);
      s2 += __shfl_xor(s2, 1, 64);
      s2 += __shfl_xor(s2, 2, 64);
      s2 += __shfl_xor(s2, 4, 64);
      s2 += __shfl_xor(s2, 8, 64);

      // online softmax, packed o-update
      {
        float mn = fmaxf(m1, s1);
        float al = __expf(m1 - mn);
        float ex = __expf(s1 - mn);
        l1 = l1 * al + ex;
        __half2 ah = __float2half2_rn(al), eh = __float2half2_rn(ex);
#pragma unroll
        for (int i = 0; i < 4; ++i)
          o1[i] = __hfma2(o1[i], ah, __hmul2(h2(v1[i]), eh));
        m1 = mn;
      }
      {
        float mn = fmaxf(m2, s2);
        float al = __expf(m2 - mn);
        float ex = __expf(s2 - mn);
        l2 = l2 * al + ex;
        __half2 ah = __float2half2_rn(al), eh = __float2half2_rn(ex);
        o2[0] = __hfma2(o2[0], ah, __hmul2(h2(v2[0]), eh));
        o2[1] = __hfma2(o2[1], ah, __hmul2(h2(v2[1]), eh));
        m2 = mn;
      }
      k1 = k1n; k2 = k2n; v1 = v1n; v2 = v2n;
    }
  }

  // unpack packed accumulators to f32 (once per wave)
  float of1[8], of2[4];
#pragma unroll
  for (int i = 0; i < 4; ++i) {
    of1[2 * i] = __low2float(o1[i]);
    of1[2 * i + 1] = __high2float(o1[i]);
  }
#pragma unroll
  for (int i = 0; i < 2; ++i) {
    of2[2 * i] = __low2float(o2[i]);
    of2[2 * i + 1] = __high2float(o2[i]);
  }

  // odd wave publishes its state (state-major: lane-contiguous, conflict-free)
  float* sb = sm + sIb * 16 * 64;
  if (half == 1) {
    sb[0 * 64 + lane] = m1;  sb[1 * 64 + lane] = l1;
    sb[2 * 64 + lane] = m2;  sb[3 * 64 + lane] = l2;
#pragma unroll
    for (int i = 0; i < 8; ++i) sb[(4 + i) * 64 + lane] = of1[i];
#pragma unroll
    for (int i = 0; i < 4; ++i) sb[(12 + i) * 64 + lane] = of2[i];
  }
  __syncthreads();
  if (half == 0) {
    float mB1 = sb[0 * 64 + lane], lB1 = sb[1 * 64 + lane];
    float mB2 = sb[2 * 64 + lane], lB2 = sb[3 * 64 + lane];

    float res1[8], res2[4];
    {
      float mn = fmaxf(fmaxf(m1, mB1), -1e30f);
      float aA = __expf(m1 - mn), aB = __expf(mB1 - mn);
      float l = l1 * aA + lB1 * aB;
      float inv = 1.f / fmaxf(l, 1e-9f);
#pragma unroll
      for (int i = 0; i < 8; ++i)
        res1[i] = (of1[i] * aA + sb[(4 + i) * 64 + lane] * aB) * inv;
    }
    {
      float mn = fmaxf(fmaxf(m2, mB2), -1e30f);
      float aA = __expf(m2 - mn), aB = __expf(mB2 - mn);
      float l = l2 * aA + lB2 * aB;
      float inv = 1.f / fmaxf(l, 1e-9f);
#pragma unroll
      for (int i = 0; i < 4; ++i)
        res2[i] = (of2[i] * aA + sb[(12 + i) * 64 + lane] * aB) * inv;
    }

    float* op = out + seg * HH;
    float4 r0 = {res1[0], res1[1], res1[2], res1[3]};
    float4 r1 = {res1[4], res1[5], res1[6], res1[7]};
    float4 r2 = {res2[0], res2[1], res2[2], res2[3]};
    ((float4*)(op + lane * 8))[0] = r0;
    ((float4*)(op + lane * 8))[1] = r1;
    *(float4*)(op + 512 + lane * 4) = r2;
  }
}

// ---------------- launch ----------------
extern "C" void kernel_launch(void* const* d_in, const int* in_sizes, int n_in,
                              void* d_out, int out_size, void* d_ws, size_t ws_size,
                              hipStream_t stream) {
  const float* X  = (const float*)d_in[0];
  const int*   EI = (const int*)d_in[1];
  const float* Wq = (const float*)d_in[2];
  const float* Wk = (const float*)d_in[3];
  const float* Wv = (const float*)d_in[4];
  float* out = (float*)d_out;
  const int E = in_sizes[1] / 4;

  // workspace layout (~56 MB)
  char* ws = (char*)d_ws;
  int* cursor  = (int*)(ws);                 // 32 KB
  int* tailrow = (int*)(ws + 32768);         // NSEG*64*4 = 2 MB
  u16* Xb      = (u16*)(ws + 2129920);       // 8192*768*2  = 12.6 MB  (f16)
  u16* Wt      = (u16*)(ws + 14712832);      // 2304*768*2  = 3.5 MB   (f16)
  u16* QKV     = (u16*)(ws + 18251776);      // 8192*2304*2 = 37.7 MB  (f16)

  hipMemsetAsync(cursor, 0, NSEG * 4, stream);
  prep_kernel<<<CAST_BLKS + TW_BLKS + BUILD_BLKS, 256, 0, stream>>>(
      X, Xb, Wq, Wk, Wv, Wt, EI, cursor, tailrow, E);
  gemm_kernel<<<dim3(QKVN / BN, NSEG / BM), 256, 0, stream>>>(Xb, Wt, QKV);
  attn_kernel<<<NSEG / 2, 256, 0, stream>>>(QKV, tailrow, cursor, out);
}

// Round 9
// 167.016 us; speedup vs baseline: 2.0438x; 1.0157x over previous
//
#include <hip/hip_runtime.h>
#include <hip/hip_fp16.h>

// Problem constants (fixed by reference)
#define BB 8
#define NN 1024
#define HH 768
#define NHEAD 12
#define HD 64
#define NSEG 8192            // B*N
#define QKVN 2304            // 3*H
#define MAXDEG 64            // bucket capacity per segment (Poisson(16); P(>64) ~ 1e-18)

typedef unsigned short u16;
typedef __attribute__((ext_vector_type(8))) _Float16 f16x8;
typedef __attribute__((ext_vector_type(4))) float f32x4;
typedef __attribute__((ext_vector_type(4))) unsigned int u32x4;
typedef __attribute__((ext_vector_type(2))) unsigned int u32x2;

__device__ __forceinline__ u16 f2h(float f) {
  _Float16 h = (_Float16)f;
  return __builtin_bit_cast(u16, h);
}
__device__ __forceinline__ __half2 h2(unsigned int w) {
  return __builtin_bit_cast(__half2, w);
}

// ---------------- fused prep: cast X, transpose W, build CSR ----------------
#define CAST_BLKS (NSEG * HH / 4 / 256)     // 6144
#define TW_BLKS   ((QKVN / 32) * (HH / 32)) // 1728
#define BUILD_BLKS 512

__global__ void prep_kernel(const float* __restrict__ X, u16* __restrict__ Xb,
                            const float* __restrict__ Wq, const float* __restrict__ Wk,
                            const float* __restrict__ Wv, u16* __restrict__ Wt,
                            const int* __restrict__ EI, int* __restrict__ cursor,
                            int* __restrict__ tailrow, int E) {
  const int bid = blockIdx.x;
  if (bid < CAST_BLKS) {
    int i = bid * 256 + threadIdx.x;
    float4 f = ((const float4*)X)[i];
    ushort4 o;
    o.x = f2h(f.x); o.y = f2h(f.y); o.z = f2h(f.z); o.w = f2h(f.w);
    ((ushort4*)Xb)[i] = o;
  } else if (bid < CAST_BLKS + TW_BLKS) {
    __shared__ float tile[32][33];
    int t = bid - CAST_BLKS;
    int n0 = (t % (QKVN / 32)) * 32;
    int k0 = (t / (QKVN / 32)) * 32;
    const float* W = (n0 < HH) ? Wq : (n0 < 2 * HH ? Wk : Wv);
    int nb = n0 - (n0 < HH ? 0 : (n0 < 2 * HH ? HH : 2 * HH));
    int tx = threadIdx.x & 31, ty = threadIdx.x >> 5;   // (32, 8)
#pragma unroll
    for (int r = 0; r < 4; ++r)
      tile[ty + 8 * r][tx] = W[(k0 + ty + 8 * r) * HH + nb + tx];
    __syncthreads();
#pragma unroll
    for (int r = 0; r < 4; ++r)
      Wt[(n0 + ty + 8 * r) * HH + k0 + tx] = f2h(tile[tx][ty + 8 * r]);
  } else {
    int e = (bid - CAST_BLKS - TW_BLKS) * 256 + threadIdx.x;
    if (e >= E) return;
    int b = EI[e];
    int seg = b * NN + EI[E + e];
    int j = EI[2 * E + e];
    int pos = atomicAdd(&cursor[seg], 1);
    if (pos < MAXDEG) tailrow[seg * MAXDEG + pos] = b * NN + j;
  }
}

// ---------------- fused QKV GEMM: (8192x768) @ (768x2304), f16 MFMA ----------------
// R6-verified depth-2 pipeline (3 LDS bufs, raw s_barrier + vmcnt(4)).
// R9: XOR-swizzled LDS chunk layout to kill the 8-way ds_read bank conflict.
//   Chunk (m, q) [16B, q = k-quad 0..3] lives at chunk index m*4 + (q ^ ((m>>1)&3)).
//   Staging: lane l of wave w writes LDS base+l*16 (hardware constraint), so it
//   must FETCH global col ((l&3) ^ ((l>>3)&3))*8 — same 64B line per 4-lane
//   group as before (coalescing unchanged), chunks permuted within the line.
//   Reads: bank-quad (4*(l15&1) + quad^((l15>>1)&3)) mod 8 covers all 8
//   bank-quads twice across 16 lanes -> 2-way aliasing = free [m136].
#define BM 128
#define BN 128
#define BK 32
#define NITER (HH / BK)   // 24

__global__ __launch_bounds__(256) void gemm_kernel(const u16* __restrict__ Xb,
                                                   const u16* __restrict__ Wt,
                                                   u16* __restrict__ QKV) {
  __shared__ u16 As[3][BM * BK];   // 3 x 8 KB
  __shared__ u16 Bs[3][BN * BK];   // 3 x 8 KB
  const int tid = threadIdx.x;
  const int wave = tid >> 6;
  const int lane = tid & 63;
  const int m0 = blockIdx.y * BM;
  const int n0 = blockIdx.x * BN;
  const int wr = wave >> 1;
  const int wc = wave & 1;
  const int quad = lane >> 4;
  const int l15 = lane & 15;

  f32x4 acc[4][4] = {};

  const int srow = wave * 16 + (lane >> 2);
  const int scol = (((lane & 3) ^ ((lane >> 3) & 3)) << 3);   // swizzled k-quad fetch
  const int rswz = quad ^ ((l15 >> 1) & 3);                    // read-side swizzle (per-lane const)

  auto stage = [&](int buf, int kt) {
#pragma unroll
    for (int p = 0; p < 2; ++p) {
      const u16* ga = Xb + (m0 + p * 64 + srow) * HH + kt + scol;
      const u16* gb = Wt + (n0 + p * 64 + srow) * HH + kt + scol;
      u16* la = As[buf] + p * 2048 + wave * 512;
      u16* lb = Bs[buf] + p * 2048 + wave * 512;
      __builtin_amdgcn_global_load_lds(
          (const __attribute__((address_space(1))) unsigned int*)(unsigned long long)ga,
          (__attribute__((address_space(3))) unsigned int*)(unsigned long long)la, 16, 0, 0);
      __builtin_amdgcn_global_load_lds(
          (const __attribute__((address_space(1))) unsigned int*)(unsigned long long)gb,
          (__attribute__((address_space(3))) unsigned int*)(unsigned long long)lb, 16, 0, 0);
    }
  };

  stage(0, 0);
  stage(1, BK);

#pragma unroll 3
  for (int it = 0; it < NITER; ++it) {
    if (it != NITER - 1) {
      asm volatile("s_waitcnt vmcnt(4)" ::: "memory");
    } else {
      asm volatile("s_waitcnt vmcnt(0)" ::: "memory");
    }
    asm volatile("s_barrier" ::: "memory");
    if (it + 2 < NITER) stage((it + 2) % 3, (it + 2) * BK);

    const int b = it % 3;
    f16x8 afr[4], bfr[4];
#pragma unroll
    for (int mi = 0; mi < 4; ++mi) {
      int m = wr * 64 + mi * 16 + l15;
      afr[mi] = *(const f16x8*)(As[b] + m * BK + rswz * 8);
    }
#pragma unroll
    for (int ni = 0; ni < 4; ++ni) {
      int n = wc * 64 + ni * 16 + l15;
      bfr[ni] = *(const f16x8*)(Bs[b] + n * BK + rswz * 8);
    }
#pragma unroll
    for (int mi = 0; mi < 4; ++mi)
#pragma unroll
      for (int ni = 0; ni < 4; ++ni)
        acc[mi][ni] = __builtin_amdgcn_mfma_f32_16x16x32_f16(afr[mi], bfr[ni], acc[mi][ni], 0, 0, 0);
  }

  // epilogue: C/D layout col=lane&15, row=(lane>>4)*4+reg  [m89-verified]
#pragma unroll
  for (int mi = 0; mi < 4; ++mi)
#pragma unroll
    for (int ni = 0; ni < 4; ++ni) {
      int col = n0 + wc * 64 + ni * 16 + l15;
#pragma unroll
      for (int r = 0; r < 4; ++r) {
        int row = m0 + wr * 64 + mi * 16 + quad * 4 + r;
        QKV[row * QKVN + col] = f2h(acc[mi][ni][r]);
      }
    }
}

// ---------------- attention: 2 waves/segment, packed-f16 math, XCD swizzle ----------------
// (unchanged from R8)
__global__ __launch_bounds__(256) void attn_kernel(const u16* __restrict__ QKV,
                                                   const int* __restrict__ tailrow,
                                                   const int* __restrict__ cursor,
                                                   float* __restrict__ out) {
  __shared__ float sm[2 * 16 * 64];   // [seg-in-block][16 states][64 lanes] = 8 KB
  const int wv = threadIdx.x >> 6;    // 0..3
  const int lane = threadIdx.x & 63;
  const int sIb = wv >> 1;            // segment within block
  const int half = wv & 1;            // which half of the edge list
  const int blk = (blockIdx.x & 7) * (NSEG / 16) + (blockIdx.x >> 3);  // XCD affinity: batch = blk/512
  const int seg = blk * 2 + sIb;
  const int base = seg * MAXDEG;
  int cnt = cursor[seg];
  if (cnt > MAXDEG) cnt = MAXDEG;
  const int myn = (cnt > half) ? ((cnt - half + 1) >> 1) : 0;   // edges at half, half+2, ...

  // preload q (scaled by 1/sqrt(64)=0.125, exact in f16)
  const u16* qrow = QKV + seg * QKVN;
  __half2 q1[4], q2[2];
  {
    u32x4 qa = *(const u32x4*)(qrow + lane * 8);
    u32x2 qb = *(const u32x2*)(qrow + 512 + lane * 4);
    const __half2 sc = __float2half2_rn(0.125f);
#pragma unroll
    for (int i = 0; i < 4; ++i) q1[i] = __hmul2(h2(qa[i]), sc);
    q2[0] = __hmul2(h2(qb[0]), sc);
    q2[1] = __hmul2(h2(qb[1]), sc);
  }

  float m1 = -__builtin_inff(), l1 = 0.f;
  float m2 = -__builtin_inff(), l2 = 0.f;
  __half2 o1[4] = {}, o2[2] = {};   // zero-init packed accumulators

  auto loadkv = [&](int row, u32x4& k1, u32x2& k2, u32x4& v1, u32x2& v2) {
    const u16* kp = QKV + row * QKVN + HH;
    k1 = *(const u32x4*)(kp + lane * 8);
    k2 = *(const u32x2*)(kp + 512 + lane * 4);
    v1 = *(const u32x4*)(kp + HH + lane * 8);
    v2 = *(const u32x2*)(kp + HH + 512 + lane * 4);
  };

  if (myn > 0) {
    u32x4 k1, v1, k1n, v1n;
    u32x2 k2, v2, k2n, v2n;
    loadkv(tailrow[base + half], k1, k2, v1, v2);
    for (int t = 0; t < myn; ++t) {
      int tn = (t + 1 < myn) ? t + 1 : t;   // clamp: harmless reload on last iter
      loadkv(tailrow[base + half + 2 * tn], k1n, k2n, v1n, v2n);

      // scores via packed f16 fma
      __half2 a1 = __hmul2(q1[0], h2(k1[0]));
      a1 = __hfma2(q1[1], h2(k1[1]), a1);
      a1 = __hfma2(q1[2], h2(k1[2]), a1);
      a1 = __hfma2(q1[3], h2(k1[3]), a1);
      float s1 = __low2float(a1) + __high2float(a1);
      s1 += __shfl_xor(s1, 1, 64);
      s1 += __shfl_xor(s1, 2, 64);
      s1 += __shfl_xor(s1, 4, 64);
      __half2 a2 = __hmul2(q2[0], h2(k2[0]));
      a2 = __hfma2(q2[1], h2(k2[1]), a2);
      float s2 = __low2float(a2) + __high2float(a2);
      s2 += __shfl_xor(s2, 1, 64);
      s2 += __shfl_xor(s2, 2, 64);
      s2 += __shfl_xor(s2, 4, 64);
      s2 += __shfl_xor(s2, 8, 64);

      // online softmax, packed o-update
      {
        float mn = fmaxf(m1, s1);
        float al = __expf(m1 - mn);
        float ex = __expf(s1 - mn);
        l1 = l1 * al + ex;
        __half2 ah = __float2half2_rn(al), eh = __float2half2_rn(ex);
#pragma unroll
        for (int i = 0; i < 4; ++i)
          o1[i] = __hfma2(o1[i], ah, __hmul2(h2(v1[i]), eh));
        m1 = mn;
      }
      {
        float mn = fmaxf(m2, s2);
        float al = __expf(m2 - mn);
        float ex = __expf(s2 - mn);
        l2 = l2 * al + ex;
        __half2 ah = __float2half2_rn(al), eh = __float2half2_rn(ex);
        o2[0] = __hfma2(o2[0], ah, __hmul2(h2(v2[0]), eh));
        o2[1] = __hfma2(o2[1], ah, __hmul2(h2(v2[1]), eh));
        m2 = mn;
      }
      k1 = k1n; k2 = k2n; v1 = v1n; v2 = v2n;
    }
  }

  // unpack packed accumulators to f32 (once per wave)
  float of1[8], of2[4];
#pragma unroll
  for (int i = 0; i < 4; ++i) {
    of1[2 * i] = __low2float(o1[i]);
    of1[2 * i + 1] = __high2float(o1[i]);
  }
#pragma unroll
  for (int i = 0; i < 2; ++i) {
    of2[2 * i] = __low2float(o2[i]);
    of2[2 * i + 1] = __high2float(o2[i]);
  }

  // odd wave publishes its state (state-major: lane-contiguous, conflict-free)
  float* sb = sm + sIb * 16 * 64;
  if (half == 1) {
    sb[0 * 64 + lane] = m1;  sb[1 * 64 + lane] = l1;
    sb[2 * 64 + lane] = m2;  sb[3 * 64 + lane] = l2;
#pragma unroll
    for (int i = 0; i < 8; ++i) sb[(4 + i) * 64 + lane] = of1[i];
#pragma unroll
    for (int i = 0; i < 4; ++i) sb[(12 + i) * 64 + lane] = of2[i];
  }
  __syncthreads();
  if (half == 0) {
    float mB1 = sb[0 * 64 + lane], lB1 = sb[1 * 64 + lane];
    float mB2 = sb[2 * 64 + lane], lB2 = sb[3 * 64 + lane];

    float res1[8], res2[4];
    {
      float mn = fmaxf(fmaxf(m1, mB1), -1e30f);
      float aA = __expf(m1 - mn), aB = __expf(mB1 - mn);
      float l = l1 * aA + lB1 * aB;
      float inv = 1.f / fmaxf(l, 1e-9f);
#pragma unroll
      for (int i = 0; i < 8; ++i)
        res1[i] = (of1[i] * aA + sb[(4 + i) * 64 + lane] * aB) * inv;
    }
    {
      float mn = fmaxf(fmaxf(m2, mB2), -1e30f);
      float aA = __expf(m2 - mn), aB = __expf(mB2 - mn);
      float l = l2 * aA + lB2 * aB;
      float inv = 1.f / fmaxf(l, 1e-9f);
#pragma unroll
      for (int i = 0; i < 4; ++i)
        res2[i] = (of2[i] * aA + sb[(12 + i) * 64 + lane] * aB) * inv;
    }

    float* op = out + seg * HH;
    float4 r0 = {res1[0], res1[1], res1[2], res1[3]};
    float4 r1 = {res1[4], res1[5], res1[6], res1[7]};
    float4 r2 = {res2[0], res2[1], res2[2], res2[3]};
    ((float4*)(op + lane * 8))[0] = r0;
    ((float4*)(op + lane * 8))[1] = r1;
    *(float4*)(op + 512 + lane * 4) = r2;
  }
}

// ---------------- launch ----------------
extern "C" void kernel_launch(void* const* d_in, const int* in_sizes, int n_in,
                              void* d_out, int out_size, void* d_ws, size_t ws_size,
                              hipStream_t stream) {
  const float* X  = (const float*)d_in[0];
  const int*   EI = (const int*)d_in[1];
  const float* Wq = (const float*)d_in[2];
  const float* Wk = (const float*)d_in[3];
  const float* Wv = (const float*)d_in[4];
  float* out = (float*)d_out;
  const int E = in_sizes[1] / 4;

  // workspace layout (~56 MB)
  char* ws = (char*)d_ws;
  int* cursor  = (int*)(ws);                 // 32 KB
  int* tailrow = (int*)(ws + 32768);         // NSEG*64*4 = 2 MB
  u16* Xb      = (u16*)(ws + 2129920);       // 8192*768*2  = 12.6 MB  (f16)
  u16* Wt      = (u16*)(ws + 14712832);      // 2304*768*2  = 3.5 MB   (f16)
  u16* QKV     = (u16*)(ws + 18251776);      // 8192*2304*2 = 37.7 MB  (f16)

  hipMemsetAsync(cursor, 0, NSEG * 4, stream);
  prep_kernel<<<CAST_BLKS + TW_BLKS + BUILD_BLKS, 256, 0, stream>>>(
      X, Xb, Wq, Wk, Wv, Wt, EI, cursor, tailrow, E);
  gemm_kernel<<<dim3(QKVN / BN, NSEG / BM), 256, 0, stream>>>(Xb, Wt, QKV);
  attn_kernel<<<NSEG / 2, 256, 0, stream>>>(QKV, tailrow, cursor, out);
}